// Round 1
// baseline (837.745 us; speedup 1.0000x reference)
//
#include <hip/hip_runtime.h>
#include <cstddef>

#define S_TOK 4096
#define CDIM 256
#define NHEADS 4
#define HDIM 64
#define LDQ 68   // padded LDS stride for 64-float rows (16B-aligned, 2-way max conflict)
#define LDX 264  // padded LDS stride for 256-float rows

// ---------------- Kernel 1: fused QKV projection ----------------
// x (b, C, S) -> q,k,v in head layout (b*4+h, S, 64); q pre-scaled by 1/8.
__global__ __launch_bounds__(256) void qkv_proj_kernel(
    const float* __restrict__ x, const float* __restrict__ w,
    const float* __restrict__ bias, float* __restrict__ qb,
    float* __restrict__ kb, float* __restrict__ vb) {
  __shared__ __align__(16) float xs[CDIM * 16];  // xs[c][si]
  const int tid = threadIdx.x;
  const int b = blockIdx.y;
  const int s0 = blockIdx.x * 16;

#pragma unroll
  for (int i = 0; i < 16; ++i) {
    int flat = i * 256 + tid;
    int c = flat >> 4, si = flat & 15;
    xs[flat] = x[((size_t)(b * CDIM + c) << 12) + (s0 + si)];
  }
  __syncthreads();

  float a0[16], a1[16], a2[16];
#pragma unroll
  for (int t = 0; t < 16; ++t) { a0[t] = 0.f; a1[t] = 0.f; a2[t] = 0.f; }

  const float* w0 = w + (size_t)tid * CDIM;          // q row
  const float* w1 = w + (size_t)(tid + 256) * CDIM;  // k row
  const float* w2 = w + (size_t)(tid + 512) * CDIM;  // v row

  for (int c = 0; c < CDIM; ++c) {
    float wv0 = w0[c], wv1 = w1[c], wv2 = w2[c];
    const float* xr = xs + c * 16;
#pragma unroll
    for (int t = 0; t < 16; ++t) {
      float xv = xr[t];
      a0[t] = fmaf(wv0, xv, a0[t]);
      a1[t] = fmaf(wv1, xv, a1[t]);
      a2[t] = fmaf(wv2, xv, a2[t]);
    }
  }

  const float bq = bias[tid], bk2 = bias[256 + tid], bv2 = bias[512 + tid];
  const int h = tid >> 6, dh = tid & 63;
  const size_t base = (((size_t)(b * NHEADS + h)) * S_TOK) * HDIM + dh;
#pragma unroll
  for (int t = 0; t < 16; ++t) {
    size_t off = base + (size_t)(s0 + t) * HDIM;
    qb[off] = (a0[t] + bq) * 0.125f;  // 1/sqrt(64) folded into q
    kb[off] = a1[t] + bk2;
    vb[off] = a2[t] + bv2;
  }
}

// ---------------- Kernel 2: flash attention (fp32 baseline) ----------------
// One block per (b*4+h, 64-row q tile). 16x16 thread grid, 4x4 register tile each.
__global__ __launch_bounds__(256) void attn_kernel(
    const float* __restrict__ qb, const float* __restrict__ kb,
    const float* __restrict__ vb, float* __restrict__ ob) {
  __shared__ __align__(16) float qT[64 * LDQ];  // qT[dd][qr]
  __shared__ __align__(16) float kT[64 * LDQ];  // kT[dd][kc]; aliased as psT[kc][qr]
  __shared__ __align__(16) float vs[64 * LDQ];  // vs[kc][dd]
  float* psT = kT;  // reuse: scores written after QK read of kT completes (extra barrier)

  const int tid = threadIdx.x;
  const int tx = tid & 15, ty = tid >> 4;  // tx: kcol/dcol group, ty: qrow group
  const int bh = blockIdx.y;
  const int q0 = blockIdx.x * 64;

  const float* qg = qb + ((size_t)bh * S_TOK + q0) * HDIM;
  const float* kg0 = kb + (size_t)bh * S_TOK * HDIM;
  const float* vg0 = vb + (size_t)bh * S_TOK * HDIM;

  // stage Q tile transposed: qT[dd][tok]
#pragma unroll
  for (int r = 0; r < 4; ++r) {
    int flat = r * 256 + tid;
    int tok = flat >> 4, ddc = flat & 15;
    float4 q4 = *(const float4*)(qg + tok * HDIM + ddc * 4);
    qT[(ddc * 4 + 0) * LDQ + tok] = q4.x;
    qT[(ddc * 4 + 1) * LDQ + tok] = q4.y;
    qT[(ddc * 4 + 2) * LDQ + tok] = q4.z;
    qT[(ddc * 4 + 3) * LDQ + tok] = q4.w;
  }

  float O[4][4];
  float m_i[4], l_i[4];
#pragma unroll
  for (int r = 0; r < 4; ++r) {
    m_i[r] = -3.0e38f;
    l_i[r] = 0.f;
#pragma unroll
    for (int i = 0; i < 4; ++i) O[r][i] = 0.f;
  }

  for (int kt = 0; kt < 64; ++kt) {
    __syncthreads();  // prev PV done (and first-iter qT visible)
    const float* kg = kg0 + (size_t)kt * 64 * HDIM;
    const float* vg = vg0 + (size_t)kt * 64 * HDIM;
#pragma unroll
    for (int r = 0; r < 4; ++r) {
      int flat = r * 256 + tid;
      int tok = flat >> 4, ddc = flat & 15;
      float4 k4 = *(const float4*)(kg + tok * HDIM + ddc * 4);
      kT[(ddc * 4 + 0) * LDQ + tok] = k4.x;
      kT[(ddc * 4 + 1) * LDQ + tok] = k4.y;
      kT[(ddc * 4 + 2) * LDQ + tok] = k4.z;
      kT[(ddc * 4 + 3) * LDQ + tok] = k4.w;
      float4 v4 = *(const float4*)(vg + tok * HDIM + ddc * 4);
      *(float4*)(vs + tok * LDQ + ddc * 4) = v4;
    }
    __syncthreads();

    // S-tile = Q^T-outer-product-K: 2 b128 + 16 FMA per dd
    float sc[4][4];
#pragma unroll
    for (int r = 0; r < 4; ++r)
#pragma unroll
      for (int j = 0; j < 4; ++j) sc[r][j] = 0.f;

#pragma unroll 8
    for (int dd = 0; dd < 64; ++dd) {
      float4 q4 = *(const float4*)(qT + dd * LDQ + ty * 4);
      float4 k4 = *(const float4*)(kT + dd * LDQ + tx * 4);
      sc[0][0] = fmaf(q4.x, k4.x, sc[0][0]);
      sc[0][1] = fmaf(q4.x, k4.y, sc[0][1]);
      sc[0][2] = fmaf(q4.x, k4.z, sc[0][2]);
      sc[0][3] = fmaf(q4.x, k4.w, sc[0][3]);
      sc[1][0] = fmaf(q4.y, k4.x, sc[1][0]);
      sc[1][1] = fmaf(q4.y, k4.y, sc[1][1]);
      sc[1][2] = fmaf(q4.y, k4.z, sc[1][2]);
      sc[1][3] = fmaf(q4.y, k4.w, sc[1][3]);
      sc[2][0] = fmaf(q4.z, k4.x, sc[2][0]);
      sc[2][1] = fmaf(q4.z, k4.y, sc[2][1]);
      sc[2][2] = fmaf(q4.z, k4.z, sc[2][2]);
      sc[2][3] = fmaf(q4.z, k4.w, sc[2][3]);
      sc[3][0] = fmaf(q4.w, k4.x, sc[3][0]);
      sc[3][1] = fmaf(q4.w, k4.y, sc[3][1]);
      sc[3][2] = fmaf(q4.w, k4.z, sc[3][2]);
      sc[3][3] = fmaf(q4.w, k4.w, sc[3][3]);
    }
    __syncthreads();  // all QK reads of kT done before psT (=kT) overwrite

    // online softmax per q-row (rows replicated across the 16 tx lanes)
    float p[4][4], alpha[4];
#pragma unroll
    for (int r = 0; r < 4; ++r) {
      float tmax = fmaxf(fmaxf(sc[r][0], sc[r][1]), fmaxf(sc[r][2], sc[r][3]));
#pragma unroll
      for (int off = 1; off < 16; off <<= 1)
        tmax = fmaxf(tmax, __shfl_xor(tmax, off));
      float mnew = fmaxf(m_i[r], tmax);
      alpha[r] = __expf(m_i[r] - mnew);
      m_i[r] = mnew;
      float rs = 0.f;
#pragma unroll
      for (int j = 0; j < 4; ++j) {
        p[r][j] = __expf(sc[r][j] - mnew);
        rs += p[r][j];
      }
#pragma unroll
      for (int off = 1; off < 16; off <<= 1) rs += __shfl_xor(rs, off);
      l_i[r] = l_i[r] * alpha[r] + rs;
#pragma unroll
      for (int i = 0; i < 4; ++i) O[r][i] *= alpha[r];
    }

    // store P transposed: psT[kc][qr] (float4 over the 4 q-rows)
#pragma unroll
    for (int j = 0; j < 4; ++j) {
      float4 pj;
      pj.x = p[0][j]; pj.y = p[1][j]; pj.z = p[2][j]; pj.w = p[3][j];
      *(float4*)(psT + (tx * 4 + j) * LDQ + ty * 4) = pj;
    }
    __syncthreads();

    // O += P * V: 2 b128 + 16 FMA per kc
#pragma unroll 8
    for (int kc = 0; kc < 64; ++kc) {
      float4 pr = *(const float4*)(psT + kc * LDQ + ty * 4);
      float4 vv = *(const float4*)(vs + kc * LDQ + tx * 4);
      O[0][0] = fmaf(pr.x, vv.x, O[0][0]);
      O[0][1] = fmaf(pr.x, vv.y, O[0][1]);
      O[0][2] = fmaf(pr.x, vv.z, O[0][2]);
      O[0][3] = fmaf(pr.x, vv.w, O[0][3]);
      O[1][0] = fmaf(pr.y, vv.x, O[1][0]);
      O[1][1] = fmaf(pr.y, vv.y, O[1][1]);
      O[1][2] = fmaf(pr.y, vv.z, O[1][2]);
      O[1][3] = fmaf(pr.y, vv.w, O[1][3]);
      O[2][0] = fmaf(pr.z, vv.x, O[2][0]);
      O[2][1] = fmaf(pr.z, vv.y, O[2][1]);
      O[2][2] = fmaf(pr.z, vv.z, O[2][2]);
      O[2][3] = fmaf(pr.z, vv.w, O[2][3]);
      O[3][0] = fmaf(pr.w, vv.x, O[3][0]);
      O[3][1] = fmaf(pr.w, vv.y, O[3][1]);
      O[3][2] = fmaf(pr.w, vv.z, O[3][2]);
      O[3][3] = fmaf(pr.w, vv.w, O[3][3]);
    }
  }

  // epilogue: write merged-head layout (b, S, C), c = h*64 + dc
  const int b = bh >> 2, h = bh & 3;
#pragma unroll
  for (int r = 0; r < 4; ++r) {
    float inv = 1.0f / l_i[r];
    float4 o4;
    o4.x = O[r][0] * inv;
    o4.y = O[r][1] * inv;
    o4.z = O[r][2] * inv;
    o4.w = O[r][3] * inv;
    size_t off = ((size_t)(b * S_TOK + q0 + ty * 4 + r)) * CDIM + h * HDIM + tx * 4;
    *(float4*)(ob + off) = o4;
  }
}

// ---------------- Kernel 3: out projection + LayerNorm + transpose out ----------
__global__ __launch_bounds__(256) void out_ln_kernel(
    const float* __restrict__ a, const float* __restrict__ w,
    const float* __restrict__ bias, const float* __restrict__ lng,
    const float* __restrict__ lnb, float* __restrict__ out) {
  __shared__ __align__(16) float ys[16 * LDX];  // [tok][c]
  const int tid = threadIdx.x;
  const int b = blockIdx.y;
  const int s0 = blockIdx.x * 16;

  const float* ag = a + ((size_t)(b * S_TOK + s0)) * CDIM;
#pragma unroll
  for (int i = 0; i < 16; ++i) ys[i * LDX + tid] = ag[i * 256 + tid];
  __syncthreads();

  float acc[16];
#pragma unroll
  for (int t = 0; t < 16; ++t) acc[t] = 0.f;
  const float* wr = w + (size_t)tid * CDIM;
  for (int c4 = 0; c4 < 64; ++c4) {
    float4 wv = *(const float4*)(wr + c4 * 4);
#pragma unroll
    for (int t = 0; t < 16; ++t) {
      float4 xv = *(const float4*)(ys + t * LDX + c4 * 4);
      acc[t] = fmaf(wv.x, xv.x, acc[t]);
      acc[t] = fmaf(wv.y, xv.y, acc[t]);
      acc[t] = fmaf(wv.z, xv.z, acc[t]);
      acc[t] = fmaf(wv.w, xv.w, acc[t]);
    }
  }
  float b0 = bias[tid];
  __syncthreads();
#pragma unroll
  for (int t = 0; t < 16; ++t) ys[t * LDX + tid] = acc[t] + b0;
  __syncthreads();

  // LayerNorm: 16 lanes per token (token = tid>>4 within block's 16 tokens)
  const int gtok = tid >> 4, l16 = tid & 15;
  float sum = 0.f, ssq = 0.f;
#pragma unroll
  for (int i = 0; i < 16; ++i) {
    float v = ys[gtok * LDX + l16 * 16 + i];
    sum += v;
    ssq += v * v;
  }
#pragma unroll
  for (int off = 1; off < 16; off <<= 1) {
    sum += __shfl_xor(sum, off);
    ssq += __shfl_xor(ssq, off);
  }
  float mu = sum * (1.f / 256.f);
  float var = ssq * (1.f / 256.f) - mu * mu;
  float rstd = rsqrtf(var + 1e-5f);
#pragma unroll
  for (int i = 0; i < 16; ++i) {
    int c = l16 * 16 + i;
    float v = ys[gtok * LDX + c];
    ys[gtok * LDX + c] = (v - mu) * rstd * lng[c] + lnb[c];
  }
  __syncthreads();
  // transposed write-out: out[b][c][s0+si], 64B-contiguous runs
#pragma unroll
  for (int i = 0; i < 16; ++i) {
    int flat = i * 256 + tid;
    int c = flat >> 4, si = flat & 15;
    out[((size_t)(b * CDIM + c) << 12) + s0 + si] = ys[si * LDX + c];
  }
}

extern "C" void kernel_launch(void* const* d_in, const int* in_sizes, int n_in,
                              void* d_out, int out_size, void* d_ws, size_t ws_size,
                              hipStream_t stream) {
  const float* x = (const float*)d_in[0];
  const float* ipw = (const float*)d_in[1];
  const float* ipb = (const float*)d_in[2];
  const float* ow = (const float*)d_in[3];
  const float* ob = (const float*)d_in[4];
  const float* lng = (const float*)d_in[5];
  const float* lnb = (const float*)d_in[6];
  float* out = (float*)d_out;
  float* ws = (float*)d_ws;
  // workspace layout (floats): q | k | v | attn_out  = 32 MiB total
  float* qb = ws;
  float* kb = ws + 2097152;
  float* vb = ws + 4194304;
  float* ab = ws + 6291456;

  qkv_proj_kernel<<<dim3(256, 2), 256, 0, stream>>>(x, ipw, ipb, qb, kb, vb);
  attn_kernel<<<dim3(64, 8), 256, 0, stream>>>(qb, kb, vb, ab);
  out_ln_kernel<<<dim3(256, 2), 256, 0, stream>>>(ab, ow, ob, lng, lnb, out);
}

// Round 3
// 422.847 us; speedup vs baseline: 1.9812x; 1.9812x over previous
//
#include <hip/hip_runtime.h>
#include <cstddef>

#define S_TOK 4096
#define CDIM 256
#define NHEADS 4
#define HDIM 64
#define LDX 264  // padded LDS stride for 256-float rows (kernel 3)
#define LSK 72   // ushort stride for Ks/Vt/Ps rows: 144B = 16B-aligned, even bank spread

typedef __attribute__((ext_vector_type(8))) short short8;
typedef __attribute__((ext_vector_type(4))) float floatx4;

__device__ inline unsigned short f2bf(float f) {
  union { float f; unsigned u; } v;
  v.f = f;
  unsigned r = v.u + 0x7fff + ((v.u >> 16) & 1);  // round-to-nearest-even
  return (unsigned short)(r >> 16);
}

// ---------------- Kernel 1: fused QKV projection (fp32 math, bf16 out) -------
// x (b, C, S) -> q16,k16 [bh][S][64] bf16 (q pre-scaled 1/8); vt16 [bh][64][S] bf16.
__global__ __launch_bounds__(256) void qkv_proj_kernel(
    const float* __restrict__ x, const float* __restrict__ w,
    const float* __restrict__ bias, unsigned short* __restrict__ q16,
    unsigned short* __restrict__ k16, unsigned short* __restrict__ vt16) {
  __shared__ __align__(16) float xs[CDIM * 16];  // xs[c][si]; reused for v packing
  const int tid = threadIdx.x;
  const int b = blockIdx.y;
  const int s0 = blockIdx.x * 16;

#pragma unroll
  for (int i = 0; i < 16; ++i) {
    int flat = i * 256 + tid;
    int c = flat >> 4, si = flat & 15;
    xs[flat] = x[((size_t)(b * CDIM + c) << 12) + (s0 + si)];
  }
  __syncthreads();

  float a0[16], a1[16], a2[16];
#pragma unroll
  for (int t = 0; t < 16; ++t) { a0[t] = 0.f; a1[t] = 0.f; a2[t] = 0.f; }

  const float* w0 = w + (size_t)tid * CDIM;
  const float* w1 = w + (size_t)(tid + 256) * CDIM;
  const float* w2 = w + (size_t)(tid + 512) * CDIM;

  for (int c = 0; c < CDIM; ++c) {
    float wv0 = w0[c], wv1 = w1[c], wv2 = w2[c];
    const float* xr = xs + c * 16;
#pragma unroll
    for (int t = 0; t < 16; ++t) {
      float xv = xr[t];
      a0[t] = fmaf(wv0, xv, a0[t]);
      a1[t] = fmaf(wv1, xv, a1[t]);
      a2[t] = fmaf(wv2, xv, a2[t]);
    }
  }

  const float bq = bias[tid], bk2 = bias[256 + tid], bv2 = bias[512 + tid];
  const int h = tid >> 6, dh = tid & 63;
  const int bh = b * NHEADS + h;
  // q,k: wave-coalesced b16 stores (64 consecutive dh per wave)
  const size_t qbase = ((size_t)bh * S_TOK + s0) * HDIM + dh;
#pragma unroll
  for (int t = 0; t < 16; ++t) {
    q16[qbase + (size_t)t * HDIM] = f2bf((a0[t] + bq) * 0.125f);
    k16[qbase + (size_t)t * HDIM] = f2bf(a1[t] + bk2);
  }
  // v: pack this thread's 16 bf16 (channel dh, tokens s0..s0+15) -> 32B store
  __syncthreads();  // all xs reads done
  unsigned short* xs16 = (unsigned short*)xs;  // stride 18 ushorts (bank-clean)
#pragma unroll
  for (int t = 0; t < 16; ++t) xs16[tid * 18 + t] = f2bf(a2[t] + bv2);
  __syncthreads();
  const unsigned* xsu = (const unsigned*)xs;
  unsigned vv[8];
#pragma unroll
  for (int j = 0; j < 8; ++j) vv[j] = xsu[tid * 9 + j];
  unsigned short* vrow = vt16 + ((size_t)bh * HDIM + dh) * S_TOK + s0;
  uint4 pa, pb2;
  pa.x = vv[0]; pa.y = vv[1]; pa.z = vv[2]; pa.w = vv[3];
  pb2.x = vv[4]; pb2.y = vv[5]; pb2.z = vv[6]; pb2.w = vv[7];
  *(uint4*)(vrow) = pa;
  *(uint4*)(vrow + 8) = pb2;
}

// ---------------- Kernel 2: flash attention, bf16 MFMA ----------------
// Block: 256 thr = 4 waves; block owns 64 q-rows of one (b,h); wave owns 16.
// Per 64-key tile: 8 MFMA QK^T + softmax + P->LDS(bf16) + 8 MFMA PV.
__global__ __launch_bounds__(256) void attn_kernel(
    const unsigned short* __restrict__ q16,
    const unsigned short* __restrict__ k16,
    const unsigned short* __restrict__ vt16, float* __restrict__ ab) {
  __shared__ __align__(16) unsigned short Ks[64 * LSK];      // [key][dd]
  __shared__ __align__(16) unsigned short Vt[64 * LSK];      // [d][key]
  __shared__ __align__(16) unsigned short Ps[4 * 16 * LSK];  // per-wave [qrow][key]

  const int tid = threadIdx.x;
  const int wave = tid >> 6;
  const int lane = tid & 63;
  const int quad = lane >> 4;
  const int l16 = lane & 15;
  const int bh = blockIdx.y;
  const int q0 = blockIdx.x * 64;

  // Q A-fragments (loop-invariant): A[m=l16][k=quad*8+j], kchunks dd 0..31/32..63
  short8 qf0, qf1;
  {
    const unsigned short* qg =
        q16 + ((size_t)bh * S_TOK + q0 + wave * 16 + l16) * HDIM + quad * 8;
    qf0 = *(const short8*)(qg);
    qf1 = *(const short8*)(qg + 32);
  }

  // staging: 8 threads per 64-elem row, 16B each; thread covers rows sr, sr+32
  const int sr = tid >> 3, scc = tid & 7;  // sr 0..31, scc 0..7
  const unsigned short* kg =
      k16 + ((size_t)bh * S_TOK + sr) * HDIM + scc * 8;
  const unsigned short* vg =
      vt16 + ((size_t)bh * HDIM + sr) * S_TOK + scc * 8;
  unsigned short* ksw = &Ks[sr * LSK + scc * 8];
  unsigned short* vtw = &Vt[sr * LSK + scc * 8];

  floatx4 O[4];  // O[nt]: rows quad*4+r, col nt*16+l16
  float m_i[4], l_i[4];
#pragma unroll
  for (int nt = 0; nt < 4; ++nt) O[nt] = (floatx4){0.f, 0.f, 0.f, 0.f};
#pragma unroll
  for (int r = 0; r < 4; ++r) { m_i[r] = -3.0e38f; l_i[r] = 0.f; }

  // prefetch tile 0 (K rows sr, sr+32; Vt rows sr, sr+32)
  uint4 k0r = *(const uint4*)(kg);
  uint4 k1r = *(const uint4*)(kg + 32 * HDIM);
  uint4 v0r = *(const uint4*)(vg);
  uint4 v1r = *(const uint4*)(vg + (size_t)32 * S_TOK);

  for (int kt = 0; kt < 64; ++kt) {
    __syncthreads();  // previous tile's LDS reads complete
    *(uint4*)ksw = k0r;
    *(uint4*)(ksw + 32 * LSK) = k1r;
    *(uint4*)vtw = v0r;
    *(uint4*)(vtw + 32 * LSK) = v1r;
    __syncthreads();
    if (kt < 63) {  // prefetch next tile during compute
      const unsigned short* kgn = kg + (size_t)(kt + 1) * 64 * HDIM;
      const unsigned short* vgn = vg + (kt + 1) * 64;
      k0r = *(const uint4*)(kgn);
      k1r = *(const uint4*)(kgn + 32 * HDIM);
      v0r = *(const uint4*)(vgn);
      v1r = *(const uint4*)(vgn + (size_t)32 * S_TOK);
    }

    // ---- S = Q K^T : B[k=dd][n=key] from Ks[key][dd]
    floatx4 sc[4];
#pragma unroll
    for (int nt = 0; nt < 4; ++nt) {
      short8 kf0 = *(const short8*)(&Ks[(nt * 16 + l16) * LSK + quad * 8]);
      short8 kf1 = *(const short8*)(&Ks[(nt * 16 + l16) * LSK + 32 + quad * 8]);
      floatx4 c = (floatx4){0.f, 0.f, 0.f, 0.f};
      c = __builtin_amdgcn_mfma_f32_16x16x32_bf16(qf0, kf0, c, 0, 0, 0);
      c = __builtin_amdgcn_mfma_f32_16x16x32_bf16(qf1, kf1, c, 0, 0, 0);
      sc[nt] = c;
    }

    // ---- online softmax; C-layout row = quad*4+r, col = nt*16+l16
    float alpha[4];
#pragma unroll
    for (int r = 0; r < 4; ++r) {
      float mx = fmaxf(fmaxf(sc[0][r], sc[1][r]), fmaxf(sc[2][r], sc[3][r]));
      mx = fmaxf(mx, __shfl_xor(mx, 1));
      mx = fmaxf(mx, __shfl_xor(mx, 2));
      mx = fmaxf(mx, __shfl_xor(mx, 4));
      mx = fmaxf(mx, __shfl_xor(mx, 8));
      float mnew = fmaxf(m_i[r], mx);
      alpha[r] = __expf(m_i[r] - mnew);
      m_i[r] = mnew;
      float p0 = __expf(sc[0][r] - mnew);
      float p1 = __expf(sc[1][r] - mnew);
      float p2 = __expf(sc[2][r] - mnew);
      float p3 = __expf(sc[3][r] - mnew);
      sc[0][r] = p0; sc[1][r] = p1; sc[2][r] = p2; sc[3][r] = p3;
      float rs = (p0 + p1) + (p2 + p3);
      rs += __shfl_xor(rs, 1);
      rs += __shfl_xor(rs, 2);
      rs += __shfl_xor(rs, 4);
      rs += __shfl_xor(rs, 8);
      l_i[r] = l_i[r] * alpha[r] + rs;
    }

    // ---- P -> wave-private LDS (C-layout -> A-layout), bf16
    unsigned short* pw = &Ps[wave * 16 * LSK];
#pragma unroll
    for (int nt = 0; nt < 4; ++nt)
#pragma unroll
      for (int r = 0; r < 4; ++r)
        pw[(quad * 4 + r) * LSK + nt * 16 + l16] = f2bf(sc[nt][r]);

    // rescale O by alpha (per row r)
#pragma unroll
    for (int nt = 0; nt < 4; ++nt)
#pragma unroll
      for (int r = 0; r < 4; ++r) O[nt][r] *= alpha[r];

    // ---- O += P V : A[m=qrow][k=key] from Ps; B[k=key][n=d] from Vt[d][key]
    short8 pf0 = *(const short8*)(&pw[l16 * LSK + quad * 8]);
    short8 pf1 = *(const short8*)(&pw[l16 * LSK + 32 + quad * 8]);
#pragma unroll
    for (int nt = 0; nt < 4; ++nt) {
      short8 vf0 = *(const short8*)(&Vt[(nt * 16 + l16) * LSK + quad * 8]);
      short8 vf1 = *(const short8*)(&Vt[(nt * 16 + l16) * LSK + 32 + quad * 8]);
      O[nt] = __builtin_amdgcn_mfma_f32_16x16x32_bf16(pf0, vf0, O[nt], 0, 0, 0);
      O[nt] = __builtin_amdgcn_mfma_f32_16x16x32_bf16(pf1, vf1, O[nt], 0, 0, 0);
    }
  }

  // epilogue: ab (b, S, C) fp32, c = h*64 + nt*16 + l16
  const int b = bh >> 2, h = bh & 3;
#pragma unroll
  for (int r = 0; r < 4; ++r) {
    float inv = 1.0f / l_i[r];
    int row = q0 + wave * 16 + quad * 4 + r;
#pragma unroll
    for (int nt = 0; nt < 4; ++nt) {
      ab[((size_t)b * S_TOK + row) * CDIM + h * 64 + nt * 16 + l16] =
          O[nt][r] * inv;
    }
  }
}

// ---------------- Kernel 3: out projection + LayerNorm + transpose out ------
__global__ __launch_bounds__(256) void out_ln_kernel(
    const float* __restrict__ a, const float* __restrict__ w,
    const float* __restrict__ bias, const float* __restrict__ lng,
    const float* __restrict__ lnb, float* __restrict__ out) {
  __shared__ __align__(16) float ys[16 * LDX];  // [tok][c]
  const int tid = threadIdx.x;
  const int b = blockIdx.y;
  const int s0 = blockIdx.x * 16;

  const float* ag = a + ((size_t)(b * S_TOK + s0)) * CDIM;
#pragma unroll
  for (int i = 0; i < 16; ++i) ys[i * LDX + tid] = ag[i * 256 + tid];
  __syncthreads();

  float acc[16];
#pragma unroll
  for (int t = 0; t < 16; ++t) acc[t] = 0.f;
  const float* wr = w + (size_t)tid * CDIM;
  for (int c4 = 0; c4 < 64; ++c4) {
    float4 wv = *(const float4*)(wr + c4 * 4);
#pragma unroll
    for (int t = 0; t < 16; ++t) {
      float4 xv = *(const float4*)(ys + t * LDX + c4 * 4);
      acc[t] = fmaf(wv.x, xv.x, acc[t]);
      acc[t] = fmaf(wv.y, xv.y, acc[t]);
      acc[t] = fmaf(wv.z, xv.z, acc[t]);
      acc[t] = fmaf(wv.w, xv.w, acc[t]);
    }
  }
  float b0 = bias[tid];
  __syncthreads();
#pragma unroll
  for (int t = 0; t < 16; ++t) ys[t * LDX + tid] = acc[t] + b0;
  __syncthreads();

  const int gtok = tid >> 4, l16 = tid & 15;
  float sum = 0.f, ssq = 0.f;
#pragma unroll
  for (int i = 0; i < 16; ++i) {
    float v = ys[gtok * LDX + l16 * 16 + i];
    sum += v;
    ssq += v * v;
  }
#pragma unroll
  for (int off = 1; off < 16; off <<= 1) {
    sum += __shfl_xor(sum, off);
    ssq += __shfl_xor(ssq, off);
  }
  float mu = sum * (1.f / 256.f);
  float var = ssq * (1.f / 256.f) - mu * mu;
  float rstd = rsqrtf(var + 1e-5f);
#pragma unroll
  for (int i = 0; i < 16; ++i) {
    int c = l16 * 16 + i;
    float v = ys[gtok * LDX + c];
    ys[gtok * LDX + c] = (v - mu) * rstd * lng[c] + lnb[c];
  }
  __syncthreads();
#pragma unroll
  for (int i = 0; i < 16; ++i) {
    int flat = i * 256 + tid;
    int c = flat >> 4, si = flat & 15;
    out[((size_t)(b * CDIM + c) << 12) + s0 + si] = ys[si * LDX + c];
  }
}

extern "C" void kernel_launch(void* const* d_in, const int* in_sizes, int n_in,
                              void* d_out, int out_size, void* d_ws, size_t ws_size,
                              hipStream_t stream) {
  const float* x = (const float*)d_in[0];
  const float* ipw = (const float*)d_in[1];
  const float* ipb = (const float*)d_in[2];
  const float* ow = (const float*)d_in[3];
  const float* ob = (const float*)d_in[4];
  const float* lng = (const float*)d_in[5];
  const float* lnb = (const float*)d_in[6];
  float* out = (float*)d_out;
  // workspace: q16 | k16 | vt16 (bf16, 4 MiB each) | ab (fp32, 8 MiB)
  unsigned short* q16 = (unsigned short*)d_ws;
  unsigned short* k16 = q16 + 2097152;
  unsigned short* vt16 = k16 + 2097152;
  float* ab = (float*)(vt16 + 2097152);

  qkv_proj_kernel<<<dim3(256, 2), 256, 0, stream>>>(x, ipw, ipb, q16, k16, vt16);
  attn_kernel<<<dim3(64, 8), 256, 0, stream>>>(q16, k16, vt16, ab);
  out_ln_kernel<<<dim3(256, 2), 256, 0, stream>>>(ab, ow, ob, lng, lnb, out);
}

// Round 4
// 249.185 us; speedup vs baseline: 3.3619x; 1.6969x over previous
//
#include <hip/hip_runtime.h>
#include <cstddef>

#define S_TOK 4096
#define CDIM 256
#define NHEADS 4
#define HDIM 64
#define LSK 72   // ushort stride for attention LDS rows
#define LDA 36   // ushort stride for GEMM LDS tiles (32 k + 4 pad)
#define LDY 264  // float stride for GEMM2 LN buffer

typedef __attribute__((ext_vector_type(8))) short short8;
typedef __attribute__((ext_vector_type(4))) float floatx4;

__device__ inline unsigned short f2bf(float f) {
  union { float f; unsigned u; } v;
  v.f = f;
  unsigned r = v.u + 0x7fff + ((v.u >> 16) & 1);  // round-to-nearest-even
  return (unsigned short)(r >> 16);
}

// ---------------- Prep 1: weights fp32 -> bf16 (in_proj_w 768x256, out_w 256x256)
__global__ __launch_bounds__(256) void convert_w_kernel(
    const float* __restrict__ ipw, const float* __restrict__ ow,
    unsigned short* __restrict__ wbf, unsigned short* __restrict__ owbf) {
  int idx = blockIdx.x * 256 + threadIdx.x;  // 65536 float4s total
  float4 f;
  unsigned short* dst;
  if (idx < 49152) {
    f = ((const float4*)ipw)[idx];
    dst = wbf + idx * 4;
  } else {
    int j = idx - 49152;
    f = ((const float4*)ow)[j];
    dst = owbf + j * 4;
  }
  ushort4 u;
  u.x = f2bf(f.x); u.y = f2bf(f.y); u.z = f2bf(f.z); u.w = f2bf(f.w);
  *(ushort4*)dst = u;
}

// ---------------- Prep 2: x (b,C,S) fp32 -> xbfT (b,S,C) bf16 ----------------
__global__ __launch_bounds__(256) void transpose_x_kernel(
    const float* __restrict__ x, unsigned short* __restrict__ xbfT) {
  __shared__ __align__(16) unsigned short T[64 * 72];  // [s][c]
  const int tid = threadIdx.x;
  const int s0 = blockIdx.x * 64, c0 = blockIdx.y * 64, b = blockIdx.z;
  const int c_l = tid >> 2, q4 = tid & 3;
  const float4* src = (const float4*)(x + (((size_t)(b * CDIM + c0 + c_l)) << 12) + s0);
#pragma unroll
  for (int i = 0; i < 4; ++i) {
    int chunk = i * 4 + q4;  // 16 float4-chunks per row
    float4 f = src[chunk];
    T[(chunk * 4 + 0) * 72 + c_l] = f2bf(f.x);
    T[(chunk * 4 + 1) * 72 + c_l] = f2bf(f.y);
    T[(chunk * 4 + 2) * 72 + c_l] = f2bf(f.z);
    T[(chunk * 4 + 3) * 72 + c_l] = f2bf(f.w);
  }
  __syncthreads();
  const int s_l = tid >> 2;
  unsigned short* drow = xbfT + ((size_t)((b << 12) + s0 + s_l)) * CDIM + c0;
#pragma unroll
  for (int i = 0; i < 2; ++i) {
    int chunk = i * 4 + q4;  // 8 chunks of 8 c each
    uint4 u = *(const uint4*)&T[s_l * 72 + chunk * 8];
    *(uint4*)(drow + chunk * 8) = u;
  }
}

// ---------------- Kernel 1: QKV projection as bf16 MFMA GEMM -----------------
// C[tok][c_out] = xbfT[tok][k] * wbf[c_out][k]; epilogue -> q16/k16/vt16 + bias.
__global__ __launch_bounds__(256) void qkv_gemm_kernel(
    const unsigned short* __restrict__ xbfT, const unsigned short* __restrict__ wbf,
    const float* __restrict__ ipb, unsigned short* __restrict__ q16,
    unsigned short* __restrict__ k16, unsigned short* __restrict__ vt16) {
  __shared__ __align__(16) unsigned short As[128 * LDA];  // [tok_l][k_l]
  __shared__ __align__(16) unsigned short Bs[128 * LDA];  // [cout_l][k_l]
  const int tid = threadIdx.x;
  const int wave = tid >> 6, lane = tid & 63;
  const int quad = lane >> 4, l16 = lane & 15;
  const int wm = wave >> 1, wn = wave & 1;
  const int n0 = blockIdx.x * 128;   // c_out base (0..640)
  const int tok0 = blockIdx.y * 128; // token base within batch
  const int b = blockIdx.z;

  // staging: thread covers rows r1 and r1+64, 16B chunk c1
  const int r1 = tid >> 2, c1 = tid & 3;
  const unsigned short* gA = xbfT + ((size_t)(b * S_TOK + tok0 + r1)) * CDIM + c1 * 8;
  const unsigned short* gB = wbf + ((size_t)(n0 + r1)) * CDIM + c1 * 8;
  unsigned short* wA = &As[r1 * LDA + c1 * 8];
  unsigned short* wB = &Bs[r1 * LDA + c1 * 8];

  floatx4 acc[4][4];
#pragma unroll
  for (int mt = 0; mt < 4; ++mt)
#pragma unroll
    for (int nt = 0; nt < 4; ++nt) acc[mt][nt] = (floatx4){0.f, 0.f, 0.f, 0.f};

  uint4 a0p = *(const uint4*)(gA);
  uint4 a1p = *(const uint4*)(gA + 64 * CDIM);
  uint4 b0p = *(const uint4*)(gB);
  uint4 b1p = *(const uint4*)(gB + 64 * CDIM);

  for (int ks = 0; ks < 8; ++ks) {
    __syncthreads();
    *(uint4*)wA = a0p;
    *(uint4*)(wA + 64 * LDA) = a1p;
    *(uint4*)wB = b0p;
    *(uint4*)(wB + 64 * LDA) = b1p;
    __syncthreads();
    if (ks < 7) {
      int off = (ks + 1) * 32;
      a0p = *(const uint4*)(gA + off);
      a1p = *(const uint4*)(gA + 64 * CDIM + off);
      b0p = *(const uint4*)(gB + off);
      b1p = *(const uint4*)(gB + 64 * CDIM + off);
    }
    short8 af[4], bf[4];
#pragma unroll
    for (int mt = 0; mt < 4; ++mt)
      af[mt] = *(const short8*)&As[(wm * 64 + mt * 16 + l16) * LDA + quad * 8];
#pragma unroll
    for (int nt = 0; nt < 4; ++nt)
      bf[nt] = *(const short8*)&Bs[(wn * 64 + nt * 16 + l16) * LDA + quad * 8];
#pragma unroll
    for (int mt = 0; mt < 4; ++mt)
#pragma unroll
      for (int nt = 0; nt < 4; ++nt)
        acc[mt][nt] = __builtin_amdgcn_mfma_f32_16x16x32_bf16(af[mt], bf[nt], acc[mt][nt], 0, 0, 0);
  }

  // epilogue: slab 0=q (scale 1/8), 1=k, 2=v (transposed store)
  const int slab = blockIdx.x >> 1;
  int cb[4];
  float bias4[4];
#pragma unroll
  for (int nt = 0; nt < 4; ++nt) {
    cb[nt] = n0 + wn * 64 + nt * 16 + l16;
    bias4[nt] = ipb[cb[nt]];
  }
  if (slab == 2) {  // v -> vt16[bh][dh][tok], pack 4 consecutive toks = 8B
#pragma unroll
    for (int mt = 0; mt < 4; ++mt) {
      int tok = tok0 + wm * 64 + mt * 16 + quad * 4;
#pragma unroll
      for (int nt = 0; nt < 4; ++nt) {
        int dh = cb[nt] & 63, h = (cb[nt] >> 6) & 3;
        ushort4 u;
        u.x = f2bf(acc[mt][nt][0] + bias4[nt]);
        u.y = f2bf(acc[mt][nt][1] + bias4[nt]);
        u.z = f2bf(acc[mt][nt][2] + bias4[nt]);
        u.w = f2bf(acc[mt][nt][3] + bias4[nt]);
        *(ushort4*)&vt16[((size_t)((b * NHEADS + h) * HDIM + dh)) * S_TOK + tok] = u;
      }
    }
  } else {
    unsigned short* dst = slab ? k16 : q16;
    const float sc = slab ? 1.0f : 0.125f;
#pragma unroll
    for (int mt = 0; mt < 4; ++mt)
#pragma unroll
      for (int nt = 0; nt < 4; ++nt) {
        int dh = cb[nt] & 63, h = (cb[nt] >> 6) & 3;
        size_t base = ((size_t)(b * NHEADS + h) * S_TOK);
#pragma unroll
        for (int r = 0; r < 4; ++r) {
          int tok = tok0 + wm * 64 + mt * 16 + quad * 4 + r;
          dst[(base + tok) * HDIM + dh] = f2bf((acc[mt][nt][r] + bias4[nt]) * sc);
        }
      }
  }
}

// ---------------- Kernel 2: flash attention, bf16 MFMA (ab out in bf16) ------
__global__ __launch_bounds__(256) void attn_kernel(
    const unsigned short* __restrict__ q16,
    const unsigned short* __restrict__ k16,
    const unsigned short* __restrict__ vt16, unsigned short* __restrict__ ab16) {
  __shared__ __align__(16) unsigned short Ks[64 * LSK];      // [key][dd]
  __shared__ __align__(16) unsigned short Vt[64 * LSK];      // [d][key]
  __shared__ __align__(16) unsigned short Ps[4 * 16 * LSK];  // per-wave [qrow][key]

  const int tid = threadIdx.x;
  const int wave = tid >> 6;
  const int lane = tid & 63;
  const int quad = lane >> 4;
  const int l16 = lane & 15;
  const int bh = blockIdx.y;
  const int q0 = blockIdx.x * 64;

  short8 qf0, qf1;
  {
    const unsigned short* qg =
        q16 + ((size_t)bh * S_TOK + q0 + wave * 16 + l16) * HDIM + quad * 8;
    qf0 = *(const short8*)(qg);
    qf1 = *(const short8*)(qg + 32);
  }

  const int sr = tid >> 3, scc = tid & 7;
  const unsigned short* kg = k16 + ((size_t)bh * S_TOK + sr) * HDIM + scc * 8;
  const unsigned short* vg = vt16 + ((size_t)bh * HDIM + sr) * S_TOK + scc * 8;
  unsigned short* ksw = &Ks[sr * LSK + scc * 8];
  unsigned short* vtw = &Vt[sr * LSK + scc * 8];

  floatx4 O[4];
  float m_i[4], l_i[4];
#pragma unroll
  for (int nt = 0; nt < 4; ++nt) O[nt] = (floatx4){0.f, 0.f, 0.f, 0.f};
#pragma unroll
  for (int r = 0; r < 4; ++r) { m_i[r] = -3.0e38f; l_i[r] = 0.f; }

  uint4 k0r = *(const uint4*)(kg);
  uint4 k1r = *(const uint4*)(kg + 32 * HDIM);
  uint4 v0r = *(const uint4*)(vg);
  uint4 v1r = *(const uint4*)(vg + (size_t)32 * S_TOK);

  for (int kt = 0; kt < 64; ++kt) {
    __syncthreads();
    *(uint4*)ksw = k0r;
    *(uint4*)(ksw + 32 * LSK) = k1r;
    *(uint4*)vtw = v0r;
    *(uint4*)(vtw + 32 * LSK) = v1r;
    __syncthreads();
    if (kt < 63) {
      const unsigned short* kgn = kg + (size_t)(kt + 1) * 64 * HDIM;
      const unsigned short* vgn = vg + (kt + 1) * 64;
      k0r = *(const uint4*)(kgn);
      k1r = *(const uint4*)(kgn + 32 * HDIM);
      v0r = *(const uint4*)(vgn);
      v1r = *(const uint4*)(vgn + (size_t)32 * S_TOK);
    }

    floatx4 sc[4];
#pragma unroll
    for (int nt = 0; nt < 4; ++nt) {
      short8 kf0 = *(const short8*)(&Ks[(nt * 16 + l16) * LSK + quad * 8]);
      short8 kf1 = *(const short8*)(&Ks[(nt * 16 + l16) * LSK + 32 + quad * 8]);
      floatx4 c = (floatx4){0.f, 0.f, 0.f, 0.f};
      c = __builtin_amdgcn_mfma_f32_16x16x32_bf16(qf0, kf0, c, 0, 0, 0);
      c = __builtin_amdgcn_mfma_f32_16x16x32_bf16(qf1, kf1, c, 0, 0, 0);
      sc[nt] = c;
    }

    float alpha[4];
#pragma unroll
    for (int r = 0; r < 4; ++r) {
      float mx = fmaxf(fmaxf(sc[0][r], sc[1][r]), fmaxf(sc[2][r], sc[3][r]));
      mx = fmaxf(mx, __shfl_xor(mx, 1));
      mx = fmaxf(mx, __shfl_xor(mx, 2));
      mx = fmaxf(mx, __shfl_xor(mx, 4));
      mx = fmaxf(mx, __shfl_xor(mx, 8));
      float mnew = fmaxf(m_i[r], mx);
      alpha[r] = __expf(m_i[r] - mnew);
      m_i[r] = mnew;
      float p0 = __expf(sc[0][r] - mnew);
      float p1 = __expf(sc[1][r] - mnew);
      float p2 = __expf(sc[2][r] - mnew);
      float p3 = __expf(sc[3][r] - mnew);
      sc[0][r] = p0; sc[1][r] = p1; sc[2][r] = p2; sc[3][r] = p3;
      float rs = (p0 + p1) + (p2 + p3);
      rs += __shfl_xor(rs, 1);
      rs += __shfl_xor(rs, 2);
      rs += __shfl_xor(rs, 4);
      rs += __shfl_xor(rs, 8);
      l_i[r] = l_i[r] * alpha[r] + rs;
    }

    unsigned short* pw = &Ps[wave * 16 * LSK];
#pragma unroll
    for (int nt = 0; nt < 4; ++nt)
#pragma unroll
      for (int r = 0; r < 4; ++r)
        pw[(quad * 4 + r) * LSK + nt * 16 + l16] = f2bf(sc[nt][r]);

#pragma unroll
    for (int nt = 0; nt < 4; ++nt)
#pragma unroll
      for (int r = 0; r < 4; ++r) O[nt][r] *= alpha[r];

    short8 pf0 = *(const short8*)(&pw[l16 * LSK + quad * 8]);
    short8 pf1 = *(const short8*)(&pw[l16 * LSK + 32 + quad * 8]);
#pragma unroll
    for (int nt = 0; nt < 4; ++nt) {
      short8 vf0 = *(const short8*)(&Vt[(nt * 16 + l16) * LSK + quad * 8]);
      short8 vf1 = *(const short8*)(&Vt[(nt * 16 + l16) * LSK + 32 + quad * 8]);
      O[nt] = __builtin_amdgcn_mfma_f32_16x16x32_bf16(pf0, vf0, O[nt], 0, 0, 0);
      O[nt] = __builtin_amdgcn_mfma_f32_16x16x32_bf16(pf1, vf1, O[nt], 0, 0, 0);
    }
  }

  const int b = bh >> 2, h = bh & 3;
#pragma unroll
  for (int r = 0; r < 4; ++r) {
    float inv = 1.0f / l_i[r];
    int row = q0 + wave * 16 + quad * 4 + r;
#pragma unroll
    for (int nt = 0; nt < 4; ++nt) {
      ab16[((size_t)b * S_TOK + row) * CDIM + h * 64 + nt * 16 + l16] =
          f2bf(O[nt][r] * inv);
    }
  }
}

// ---------------- Kernel 3: out projection (MFMA) + LayerNorm + transpose ----
// Block: 32 tokens x 256 c_out full; wave owns 64 c_out. Grid 256 blocks.
__global__ __launch_bounds__(256) void out_ln_gemm_kernel(
    const unsigned short* __restrict__ ab16, const unsigned short* __restrict__ owbf,
    const float* __restrict__ obias, const float* __restrict__ lng,
    const float* __restrict__ lnb, float* __restrict__ out) {
  __shared__ __align__(16) unsigned short As[32 * LDA];
  __shared__ __align__(16) unsigned short Bs[256 * LDA];
  __shared__ __align__(16) float ys[32 * LDY];
  const int tid = threadIdx.x;
  const int wave = tid >> 6, lane = tid & 63;
  const int quad = lane >> 4, l16 = lane & 15;
  const int tok0 = blockIdx.x * 32;  // global token (b folded)

  // As staging: 32 rows x 64B; thread: row tid>>3, 8B chunk tid&7
  const int ar = tid >> 3, ac = tid & 7;
  const unsigned short* gA = ab16 + ((size_t)(tok0 + ar)) * CDIM + ac * 4;
  unsigned short* wAp = &As[ar * LDA + ac * 4];
  // Bs staging: 256 rows x 64B; thread: rows (tid>>2)+64i, 16B chunk tid&3
  const int br = tid >> 2, bc = tid & 3;
  const unsigned short* gB = owbf + ((size_t)br) * CDIM + bc * 8;
  unsigned short* wBp = &Bs[br * LDA + bc * 8];

  floatx4 acc[2][4];
#pragma unroll
  for (int mt = 0; mt < 2; ++mt)
#pragma unroll
    for (int nt = 0; nt < 4; ++nt) acc[mt][nt] = (floatx4){0.f, 0.f, 0.f, 0.f};

  uint2 ap = *(const uint2*)(gA);
  uint4 bp[4];
#pragma unroll
  for (int i = 0; i < 4; ++i) bp[i] = *(const uint4*)(gB + (size_t)i * 64 * CDIM);

  for (int ks = 0; ks < 8; ++ks) {
    __syncthreads();
    *(uint2*)wAp = ap;
#pragma unroll
    for (int i = 0; i < 4; ++i) *(uint4*)(wBp + i * 64 * LDA) = bp[i];
    __syncthreads();
    if (ks < 7) {
      int off = (ks + 1) * 32;
      ap = *(const uint2*)(gA + off);
#pragma unroll
      for (int i = 0; i < 4; ++i)
        bp[i] = *(const uint4*)(gB + (size_t)i * 64 * CDIM + off);
    }
    short8 af[2], bf[4];
#pragma unroll
    for (int mt = 0; mt < 2; ++mt)
      af[mt] = *(const short8*)&As[(mt * 16 + l16) * LDA + quad * 8];
#pragma unroll
    for (int nt = 0; nt < 4; ++nt)
      bf[nt] = *(const short8*)&Bs[(wave * 64 + nt * 16 + l16) * LDA + quad * 8];
#pragma unroll
    for (int mt = 0; mt < 2; ++mt)
#pragma unroll
      for (int nt = 0; nt < 4; ++nt)
        acc[mt][nt] = __builtin_amdgcn_mfma_f32_16x16x32_bf16(af[mt], bf[nt], acc[mt][nt], 0, 0, 0);
  }

  // epilogue: +bias -> ys[tok_l][c]
#pragma unroll
  for (int mt = 0; mt < 2; ++mt)
#pragma unroll
    for (int nt = 0; nt < 4; ++nt) {
      int c = wave * 64 + nt * 16 + l16;
      float bo = obias[c];
#pragma unroll
      for (int r = 0; r < 4; ++r)
        ys[(mt * 16 + quad * 4 + r) * LDY + c] = acc[mt][nt][r] + bo;
    }
  __syncthreads();

  // LayerNorm: 8 lanes per token, c = i*8 + l8 (bank-clean)
  const int gtok = tid >> 3, l8 = tid & 7;
  float sum = 0.f, ssq = 0.f;
#pragma unroll
  for (int i = 0; i < 32; ++i) {
    float v = ys[gtok * LDY + i * 8 + l8];
    sum += v;
    ssq += v * v;
  }
  sum += __shfl_xor(sum, 1); ssq += __shfl_xor(ssq, 1);
  sum += __shfl_xor(sum, 2); ssq += __shfl_xor(ssq, 2);
  sum += __shfl_xor(sum, 4); ssq += __shfl_xor(ssq, 4);
  float mu = sum * (1.f / 256.f);
  float var = ssq * (1.f / 256.f) - mu * mu;
  float rstd = rsqrtf(var + 1e-5f);
  const int b2 = tok0 >> 12;
  const int sl = (tok0 & 4095) + gtok;
#pragma unroll
  for (int i = 0; i < 32; ++i) {
    int c = i * 8 + l8;
    float v = ys[gtok * LDY + c];
    out[(((size_t)(b2 * CDIM + c)) << 12) + sl] = (v - mu) * rstd * lng[c] + lnb[c];
  }
}

extern "C" void kernel_launch(void* const* d_in, const int* in_sizes, int n_in,
                              void* d_out, int out_size, void* d_ws, size_t ws_size,
                              hipStream_t stream) {
  const float* x = (const float*)d_in[0];
  const float* ipw = (const float*)d_in[1];
  const float* ipb = (const float*)d_in[2];
  const float* ow = (const float*)d_in[3];
  const float* ob = (const float*)d_in[4];
  const float* lng = (const float*)d_in[5];
  const float* lnb = (const float*)d_in[6];
  float* out = (float*)d_out;
  // workspace (ushort units): wbf | owbf | xbfT | q16 | k16 | vt16 | ab16
  unsigned short* wbf = (unsigned short*)d_ws;
  unsigned short* owbf = wbf + 196608;
  unsigned short* xbfT = owbf + 65536;
  unsigned short* q16 = xbfT + 2097152;
  unsigned short* k16 = q16 + 2097152;
  unsigned short* vt16 = k16 + 2097152;
  unsigned short* ab16 = vt16 + 2097152;

  convert_w_kernel<<<256, 256, 0, stream>>>(ipw, ow, wbf, owbf);
  transpose_x_kernel<<<dim3(64, 4, 2), 256, 0, stream>>>(x, xbfT);
  qkv_gemm_kernel<<<dim3(6, 32, 2), 256, 0, stream>>>(xbfT, wbf, ipb, q16, k16, vt16);
  attn_kernel<<<dim3(64, 8), 256, 0, stream>>>(q16, k16, vt16, ab16);
  out_ln_gemm_kernel<<<256, 256, 0, stream>>>(ab16, owbf, ob, lng, lnb, out);
}

// Round 5
// 182.731 us; speedup vs baseline: 4.5846x; 1.3637x over previous
//
#include <hip/hip_runtime.h>
#include <cstddef>

#define S_TOK 4096
#define CDIM 256
#define NHEADS 4
#define HDIM 64
#define LSK 72   // ushort stride for attention LDS rows
#define LDA 36   // ushort stride for GEMM LDS tiles (32 k + 4 pad)
#define LDY 264  // float stride for GEMM2 LN buffer
#define LOG2E 1.44269504f

typedef __attribute__((ext_vector_type(8))) short short8;
typedef __attribute__((ext_vector_type(4))) float floatx4;

__device__ inline unsigned short f2bf(float f) {
  union { float f; unsigned u; } v;
  v.f = f;
  unsigned r = v.u + 0x7fff + ((v.u >> 16) & 1);  // round-to-nearest-even
  return (unsigned short)(r >> 16);
}
__device__ inline float bf2f(unsigned short u) {
  union { unsigned u; float f; } v;
  v.u = ((unsigned)u) << 16;
  return v.f;
}

// ---------------- Prep 1: weights fp32 -> bf16 ----------------
__global__ __launch_bounds__(256) void convert_w_kernel(
    const float* __restrict__ ipw, const float* __restrict__ ow,
    unsigned short* __restrict__ wbf, unsigned short* __restrict__ owbf) {
  int idx = blockIdx.x * 256 + threadIdx.x;  // 65536 float4s total
  float4 f;
  unsigned short* dst;
  if (idx < 49152) {
    f = ((const float4*)ipw)[idx];
    dst = wbf + idx * 4;
  } else {
    int j = idx - 49152;
    f = ((const float4*)ow)[j];
    dst = owbf + j * 4;
  }
  ushort4 u;
  u.x = f2bf(f.x); u.y = f2bf(f.y); u.z = f2bf(f.z); u.w = f2bf(f.w);
  *(ushort4*)dst = u;
}

// ---------------- Prep 2: x (b,C,S) fp32 -> xbfT (b,S,C) bf16 ----------------
__global__ __launch_bounds__(256) void transpose_x_kernel(
    const float* __restrict__ x, unsigned short* __restrict__ xbfT) {
  __shared__ __align__(16) unsigned short T[64 * 72];  // [s][c]
  const int tid = threadIdx.x;
  const int s0 = blockIdx.x * 64, c0 = blockIdx.y * 64, b = blockIdx.z;
  const int c_l = tid >> 2, q4 = tid & 3;
  const float4* src = (const float4*)(x + (((size_t)(b * CDIM + c0 + c_l)) << 12) + s0);
#pragma unroll
  for (int i = 0; i < 4; ++i) {
    int chunk = i * 4 + q4;
    float4 f = src[chunk];
    T[(chunk * 4 + 0) * 72 + c_l] = f2bf(f.x);
    T[(chunk * 4 + 1) * 72 + c_l] = f2bf(f.y);
    T[(chunk * 4 + 2) * 72 + c_l] = f2bf(f.z);
    T[(chunk * 4 + 3) * 72 + c_l] = f2bf(f.w);
  }
  __syncthreads();
  const int s_l = tid >> 2;
  unsigned short* drow = xbfT + ((size_t)((b << 12) + s0 + s_l)) * CDIM + c0;
#pragma unroll
  for (int i = 0; i < 2; ++i) {
    int chunk = i * 4 + q4;
    uint4 u = *(const uint4*)&T[s_l * 72 + chunk * 8];
    *(uint4*)(drow + chunk * 8) = u;
  }
}

// ---------------- Kernel 1: QKV projection, bf16 MFMA GEMM (128x64 tiles) ----
// q prescale = (1/8)*log2(e) so attention scores are already log2-domain.
__global__ __launch_bounds__(256) void qkv_gemm_kernel(
    const unsigned short* __restrict__ xbfT, const unsigned short* __restrict__ wbf,
    const float* __restrict__ ipb, unsigned short* __restrict__ q16,
    unsigned short* __restrict__ k16, unsigned short* __restrict__ vt16) {
  __shared__ __align__(16) unsigned short As[128 * LDA];  // [tok_l][k_l]
  __shared__ __align__(16) unsigned short Bs[64 * LDA];   // [cout_l][k_l]
  const int tid = threadIdx.x;
  const int wave = tid >> 6, lane = tid & 63;
  const int quad = lane >> 4, l16 = lane & 15;
  const int n0 = blockIdx.x * 64;    // c_out base (0..704)
  const int tok0 = blockIdx.y * 128; // token base within batch
  const int b = blockIdx.z;

  const int r1 = tid >> 2, c1 = tid & 3;  // A: rows r1, r1+64; 16B chunk c1
  const unsigned short* gA = xbfT + ((size_t)(b * S_TOK + tok0 + r1)) * CDIM + c1 * 8;
  const unsigned short* gB = wbf + ((size_t)(n0 + r1)) * CDIM + c1 * 8;  // B: 64 rows
  unsigned short* wA = &As[r1 * LDA + c1 * 8];
  unsigned short* wB = &Bs[r1 * LDA + c1 * 8];

  floatx4 acc[2][4];
#pragma unroll
  for (int mt = 0; mt < 2; ++mt)
#pragma unroll
    for (int nt = 0; nt < 4; ++nt) acc[mt][nt] = (floatx4){0.f, 0.f, 0.f, 0.f};

  uint4 a0p = *(const uint4*)(gA);
  uint4 a1p = *(const uint4*)(gA + 64 * CDIM);
  uint4 b0p = *(const uint4*)(gB);

  for (int ks = 0; ks < 8; ++ks) {
    __syncthreads();
    *(uint4*)wA = a0p;
    *(uint4*)(wA + 64 * LDA) = a1p;
    *(uint4*)wB = b0p;
    __syncthreads();
    if (ks < 7) {
      int off = (ks + 1) * 32;
      a0p = *(const uint4*)(gA + off);
      a1p = *(const uint4*)(gA + 64 * CDIM + off);
      b0p = *(const uint4*)(gB + off);
    }
    short8 af[2], bf[4];
#pragma unroll
    for (int mt = 0; mt < 2; ++mt)
      af[mt] = *(const short8*)&As[(wave * 32 + mt * 16 + l16) * LDA + quad * 8];
#pragma unroll
    for (int nt = 0; nt < 4; ++nt)
      bf[nt] = *(const short8*)&Bs[(nt * 16 + l16) * LDA + quad * 8];
#pragma unroll
    for (int mt = 0; mt < 2; ++mt)
#pragma unroll
      for (int nt = 0; nt < 4; ++nt)
        acc[mt][nt] = __builtin_amdgcn_mfma_f32_16x16x32_bf16(af[mt], bf[nt], acc[mt][nt], 0, 0, 0);
  }

  const int slab = n0 >> 8;  // 0=q, 1=k, 2=v
  int cb[4];
  float bias4[4];
#pragma unroll
  for (int nt = 0; nt < 4; ++nt) {
    cb[nt] = n0 + nt * 16 + l16;
    bias4[nt] = ipb[cb[nt]];
  }
  if (slab == 2) {  // v -> vt16[bh][dh][tok]
#pragma unroll
    for (int mt = 0; mt < 2; ++mt) {
      int tok = tok0 + wave * 32 + mt * 16 + quad * 4;
#pragma unroll
      for (int nt = 0; nt < 4; ++nt) {
        int dh = cb[nt] & 63, h = (cb[nt] >> 6) & 3;
        ushort4 u;
        u.x = f2bf(acc[mt][nt][0] + bias4[nt]);
        u.y = f2bf(acc[mt][nt][1] + bias4[nt]);
        u.z = f2bf(acc[mt][nt][2] + bias4[nt]);
        u.w = f2bf(acc[mt][nt][3] + bias4[nt]);
        *(ushort4*)&vt16[((size_t)((b * NHEADS + h) * HDIM + dh)) * S_TOK + tok] = u;
      }
    }
  } else {
    unsigned short* dst = slab ? k16 : q16;
    const float sc = slab ? 1.0f : 0.125f * LOG2E;
#pragma unroll
    for (int mt = 0; mt < 2; ++mt)
#pragma unroll
      for (int nt = 0; nt < 4; ++nt) {
        int dh = cb[nt] & 63, h = (cb[nt] >> 6) & 3;
        size_t base = ((size_t)(b * NHEADS + h) * S_TOK);
#pragma unroll
        for (int r = 0; r < 4; ++r) {
          int tok = tok0 + wave * 32 + mt * 16 + quad * 4 + r;
          dst[(base + tok) * HDIM + dh] = f2bf((acc[mt][nt][r] + bias4[nt]) * sc);
        }
      }
  }
}

// ---------------- Kernel 2: flash attention, fixed-max softmax, key-split ----
// Grid (64 q-tiles, 8 bh, 2 key-splits). Block: 4 waves x 16 q-rows, 32 key-tiles.
// Writes unnormalized bf16 O-partials + fp32 l-partials per split.
__global__ __launch_bounds__(256) void attn_kernel(
    const unsigned short* __restrict__ q16,
    const unsigned short* __restrict__ k16,
    const unsigned short* __restrict__ vt16,
    unsigned short* __restrict__ op, float* __restrict__ lp) {
  __shared__ __align__(16) unsigned short Ks[64 * LSK];      // [key][dd]
  __shared__ __align__(16) unsigned short Vt[64 * LSK];      // [d][key]
  __shared__ __align__(16) unsigned short Ps[4 * 16 * LSK];  // per-wave [qrow][key]

  const int tid = threadIdx.x;
  const int wave = tid >> 6;
  const int lane = tid & 63;
  const int quad = lane >> 4;
  const int l16 = lane & 15;
  const int bh = blockIdx.y;
  const int q0 = blockIdx.x * 64;
  const int split = blockIdx.z;
  const int kt0 = split * 32;

  short8 qf0, qf1;
  {
    const unsigned short* qg =
        q16 + ((size_t)bh * S_TOK + q0 + wave * 16 + l16) * HDIM + quad * 8;
    qf0 = *(const short8*)(qg);
    qf1 = *(const short8*)(qg + 32);
  }

  const int sr = tid >> 3, scc = tid & 7;
  const unsigned short* kg = k16 + ((size_t)bh * S_TOK + sr) * HDIM + scc * 8;
  const unsigned short* vg = vt16 + ((size_t)bh * HDIM + sr) * S_TOK + scc * 8;
  unsigned short* ksw = &Ks[sr * LSK + scc * 8];
  unsigned short* vtw = &Vt[sr * LSK + scc * 8];

  floatx4 O[4];
  float lsum[4];
#pragma unroll
  for (int nt = 0; nt < 4; ++nt) O[nt] = (floatx4){0.f, 0.f, 0.f, 0.f};
#pragma unroll
  for (int r = 0; r < 4; ++r) lsum[r] = 0.f;

  uint4 k0r = *(const uint4*)(kg + (size_t)kt0 * 64 * HDIM);
  uint4 k1r = *(const uint4*)(kg + (size_t)kt0 * 64 * HDIM + 32 * HDIM);
  uint4 v0r = *(const uint4*)(vg + kt0 * 64);
  uint4 v1r = *(const uint4*)(vg + kt0 * 64 + (size_t)32 * S_TOK);

  for (int t = 0; t < 32; ++t) {
    __syncthreads();
    *(uint4*)ksw = k0r;
    *(uint4*)(ksw + 32 * LSK) = k1r;
    *(uint4*)vtw = v0r;
    *(uint4*)(vtw + 32 * LSK) = v1r;
    __syncthreads();
    if (t < 31) {
      const unsigned short* kgn = kg + (size_t)(kt0 + t + 1) * 64 * HDIM;
      const unsigned short* vgn = vg + (kt0 + t + 1) * 64;
      k0r = *(const uint4*)(kgn);
      k1r = *(const uint4*)(kgn + 32 * HDIM);
      v0r = *(const uint4*)(vgn);
      v1r = *(const uint4*)(vgn + (size_t)32 * S_TOK);
    }

    // ---- S_log2 = Q K^T (log2e folded into q)
    floatx4 sc[4];
#pragma unroll
    for (int nt = 0; nt < 4; ++nt) {
      short8 kf0 = *(const short8*)(&Ks[(nt * 16 + l16) * LSK + quad * 8]);
      short8 kf1 = *(const short8*)(&Ks[(nt * 16 + l16) * LSK + 32 + quad * 8]);
      floatx4 c = (floatx4){0.f, 0.f, 0.f, 0.f};
      c = __builtin_amdgcn_mfma_f32_16x16x32_bf16(qf0, kf0, c, 0, 0, 0);
      c = __builtin_amdgcn_mfma_f32_16x16x32_bf16(qf1, kf1, c, 0, 0, 0);
      sc[nt] = c;
    }

    // ---- fixed-max softmax: p = 2^score, no reductions in the loop
    unsigned short* pw = &Ps[wave * 16 * LSK];
#pragma unroll
    for (int nt = 0; nt < 4; ++nt) {
#pragma unroll
      for (int r = 0; r < 4; ++r) {
        float p = __builtin_amdgcn_exp2f(sc[nt][r]);
        lsum[r] += p;
        pw[(quad * 4 + r) * LSK + nt * 16 + l16] = f2bf(p);
      }
    }

    // ---- O += P V
    short8 pf0 = *(const short8*)(&pw[l16 * LSK + quad * 8]);
    short8 pf1 = *(const short8*)(&pw[l16 * LSK + 32 + quad * 8]);
#pragma unroll
    for (int nt = 0; nt < 4; ++nt) {
      short8 vf0 = *(const short8*)(&Vt[(nt * 16 + l16) * LSK + quad * 8]);
      short8 vf1 = *(const short8*)(&Vt[(nt * 16 + l16) * LSK + 32 + quad * 8]);
      O[nt] = __builtin_amdgcn_mfma_f32_16x16x32_bf16(pf0, vf0, O[nt], 0, 0, 0);
      O[nt] = __builtin_amdgcn_mfma_f32_16x16x32_bf16(pf1, vf1, O[nt], 0, 0, 0);
    }
  }

  // epilogue: one l-reduction; write bf16 O-partials + fp32 l-partials
  unsigned short* op_s = op + (size_t)split * 2097152;
  float* lp_s = lp + (size_t)split * 32768;
#pragma unroll
  for (int r = 0; r < 4; ++r) {
    float ls = lsum[r];
    ls += __shfl_xor(ls, 1);
    ls += __shfl_xor(ls, 2);
    ls += __shfl_xor(ls, 4);
    ls += __shfl_xor(ls, 8);
    int row = q0 + wave * 16 + quad * 4 + r;
#pragma unroll
    for (int nt = 0; nt < 4; ++nt)
      op_s[((size_t)bh * S_TOK + row) * HDIM + nt * 16 + l16] = f2bf(O[nt][r]);
    if (l16 == 0) lp_s[bh * S_TOK + row] = ls;
  }
}

// ---------------- Kernel 2b: merge key-split partials -> ab16 (b,S,C) --------
__global__ __launch_bounds__(256) void merge_kernel(
    const unsigned short* __restrict__ op, const float* __restrict__ lp,
    unsigned short* __restrict__ ab16) {
  int idx = blockIdx.x * 256 + threadIdx.x;  // 262144 threads
  int row = idx >> 3;                        // bh*4096+tok
  int ch = idx & 7;                          // dh octet
  const unsigned short* p0 = op + (size_t)row * HDIM + ch * 8;
  const unsigned short* p1 = p0 + 2097152;
  float rinv = 1.0f / (lp[row] + lp[32768 + row]);
  uint4 a = *(const uint4*)p0;
  uint4 b4 = *(const uint4*)p1;
  const unsigned* au = (const unsigned*)&a;
  const unsigned* bu = (const unsigned*)&b4;
  ushort4 o[2];
#pragma unroll
  for (int i = 0; i < 4; ++i) {
    unsigned av = au[i], bv = bu[i];
    float lo = (bf2f((unsigned short)(av & 0xffff)) + bf2f((unsigned short)(bv & 0xffff))) * rinv;
    float hi = (bf2f((unsigned short)(av >> 16)) + bf2f((unsigned short)(bv >> 16))) * rinv;
    ((unsigned short*)o)[i * 2] = f2bf(lo);
    ((unsigned short*)o)[i * 2 + 1] = f2bf(hi);
  }
  int bh = row >> 12, tok = row & 4095;
  int b = bh >> 2, h = bh & 3;
  *(ushort4*)&ab16[((size_t)(b * S_TOK + tok)) * CDIM + h * HDIM + ch * 8] = o[0];
  // second half of the octet (elements 4..7) -> o[1] is contiguous after o[0]
  *(ushort4*)&ab16[((size_t)(b * S_TOK + tok)) * CDIM + h * HDIM + ch * 8 + 4] = o[1];
}

// ---------------- Kernel 3: out projection (MFMA) + LayerNorm + transpose ----
// Block: 16 tokens x 256 c_out; wave owns 64 c_out. Grid 512 blocks.
__global__ __launch_bounds__(256) void out_ln_gemm_kernel(
    const unsigned short* __restrict__ ab16, const unsigned short* __restrict__ owbf,
    const float* __restrict__ obias, const float* __restrict__ lng,
    const float* __restrict__ lnb, float* __restrict__ out) {
  __shared__ __align__(16) unsigned short As[16 * LDA];
  __shared__ __align__(16) unsigned short Bs[256 * LDA];
  __shared__ __align__(16) float ys[16 * LDY];
  const int tid = threadIdx.x;
  const int wave = tid >> 6, lane = tid & 63;
  const int quad = lane >> 4, l16 = lane & 15;
  const int tok0 = blockIdx.x * 16;  // global token (b folded)

  // As staging: 16 rows x 16 4B-chunks
  const int ar = tid >> 4, ac = tid & 15;
  const unsigned short* gA = ab16 + ((size_t)(tok0 + ar)) * CDIM + ac * 2;
  unsigned short* wAp = &As[ar * LDA + ac * 2];
  // Bs staging: 256 rows (4 groups of 64) x 4 16B-chunks
  const int br = tid >> 2, bc = tid & 3;
  const unsigned short* gB = owbf + ((size_t)br) * CDIM + bc * 8;
  unsigned short* wBp = &Bs[br * LDA + bc * 8];

  floatx4 acc[4];
#pragma unroll
  for (int nt = 0; nt < 4; ++nt) acc[nt] = (floatx4){0.f, 0.f, 0.f, 0.f};

  unsigned ap = *(const unsigned*)(gA);
  uint4 bp[4];
#pragma unroll
  for (int i = 0; i < 4; ++i) bp[i] = *(const uint4*)(gB + (size_t)i * 64 * CDIM);

  for (int ks = 0; ks < 8; ++ks) {
    __syncthreads();
    *(unsigned*)wAp = ap;
#pragma unroll
    for (int i = 0; i < 4; ++i) *(uint4*)(wBp + i * 64 * LDA) = bp[i];
    __syncthreads();
    if (ks < 7) {
      int off = (ks + 1) * 32;
      ap = *(const unsigned*)(gA + off);
#pragma unroll
      for (int i = 0; i < 4; ++i)
        bp[i] = *(const uint4*)(gB + (size_t)i * 64 * CDIM + off);
    }
    short8 af = *(const short8*)&As[l16 * LDA + quad * 8];
    short8 bf[4];
#pragma unroll
    for (int nt = 0; nt < 4; ++nt)
      bf[nt] = *(const short8*)&Bs[(wave * 64 + nt * 16 + l16) * LDA + quad * 8];
#pragma unroll
    for (int nt = 0; nt < 4; ++nt)
      acc[nt] = __builtin_amdgcn_mfma_f32_16x16x32_bf16(af, bf[nt], acc[nt], 0, 0, 0);
  }

  // epilogue: +bias -> ys[tok_l][c]
#pragma unroll
  for (int nt = 0; nt < 4; ++nt) {
    int c = wave * 64 + nt * 16 + l16;
    float bo = obias[c];
#pragma unroll
    for (int r = 0; r < 4; ++r)
      ys[(quad * 4 + r) * LDY + c] = acc[nt][r] + bo;
  }
  __syncthreads();

  // LayerNorm: 16 lanes per token
  const int gtok = tid >> 4, lx = tid & 15;
  float sum = 0.f, ssq = 0.f;
#pragma unroll
  for (int i = 0; i < 16; ++i) {
    float v = ys[gtok * LDY + i * 16 + lx];
    sum += v;
    ssq += v * v;
  }
  sum += __shfl_xor(sum, 1); ssq += __shfl_xor(ssq, 1);
  sum += __shfl_xor(sum, 2); ssq += __shfl_xor(ssq, 2);
  sum += __shfl_xor(sum, 4); ssq += __shfl_xor(ssq, 4);
  sum += __shfl_xor(sum, 8); ssq += __shfl_xor(ssq, 8);
  float mu = sum * (1.f / 256.f);
  float var = ssq * (1.f / 256.f) - mu * mu;
  float rstd = rsqrtf(var + 1e-5f);
  const int b2 = tok0 >> 12;
  const int sl = (tok0 & 4095) + gtok;
#pragma unroll
  for (int i = 0; i < 16; ++i) {
    int c = i * 16 + lx;
    float v = ys[gtok * LDY + c];
    out[(((size_t)(b2 * CDIM + c)) << 12) + sl] = (v - mu) * rstd * lng[c] + lnb[c];
  }
}

extern "C" void kernel_launch(void* const* d_in, const int* in_sizes, int n_in,
                              void* d_out, int out_size, void* d_ws, size_t ws_size,
                              hipStream_t stream) {
  const float* x = (const float*)d_in[0];
  const float* ipw = (const float*)d_in[1];
  const float* ipb = (const float*)d_in[2];
  const float* ow = (const float*)d_in[3];
  const float* ob = (const float*)d_in[4];
  const float* lng = (const float*)d_in[5];
  const float* lnb = (const float*)d_in[6];
  float* out = (float*)d_out;
  // workspace (ushort units), total ~28.8 MiB:
  unsigned short* wbf = (unsigned short*)d_ws;       // 196608
  unsigned short* owbf = wbf + 196608;               // 65536
  unsigned short* xbfT = owbf + 65536;               // 2097152
  unsigned short* q16 = xbfT + 2097152;              // 2097152
  unsigned short* k16 = q16 + 2097152;               // 2097152
  unsigned short* vt16 = k16 + 2097152;              // 2097152
  unsigned short* op = vt16 + 2097152;               // 2 x 2097152 (bf16 O-partials)
  unsigned short* ab16 = op + 4194304;               // 2097152
  float* lp = (float*)(ab16 + 2097152);              // 2 x 32768 fp32

  convert_w_kernel<<<256, 256, 0, stream>>>(ipw, ow, wbf, owbf);
  transpose_x_kernel<<<dim3(64, 4, 2), 256, 0, stream>>>(x, xbfT);
  qkv_gemm_kernel<<<dim3(12, 32, 2), 256, 0, stream>>>(xbfT, wbf, ipb, q16, k16, vt16);
  attn_kernel<<<dim3(64, 8, 2), 256, 0, stream>>>(q16, k16, vt16, op, lp);
  merge_kernel<<<1024, 256, 0, stream>>>(op, lp, ab16);
  out_ln_gemm_kernel<<<512, 256, 0, stream>>>(ab16, owbf, ob, lng, lnb, out);
}

// Round 6
// 173.454 us; speedup vs baseline: 4.8298x; 1.0535x over previous
//
#include <hip/hip_runtime.h>
#include <cstddef>

#define S_TOK 4096
#define CDIM 256
#define NHEADS 4
#define HDIM 64
#define LSK 72   // ushort stride for attention LDS rows
#define LDA 36   // ushort stride for GEMM LDS tiles (32 k + 4 pad)
#define LDY 264  // float stride for GEMM2 LN buffer
#define LOG2E 1.44269504f

typedef __attribute__((ext_vector_type(8))) short short8;
typedef __attribute__((ext_vector_type(4))) float floatx4;

__device__ inline unsigned short f2bf(float f) {
  union { float f; unsigned u; } v;
  v.f = f;
  unsigned r = v.u + 0x7fff + ((v.u >> 16) & 1);  // round-to-nearest-even
  return (unsigned short)(r >> 16);
}
__device__ inline float bf2f(unsigned short u) {
  union { unsigned u; float f; } v;
  v.u = ((unsigned)u) << 16;
  return v.f;
}

// ---------------- Prep 1: weights fp32 -> bf16 ----------------
__global__ __launch_bounds__(256) void convert_w_kernel(
    const float* __restrict__ ipw, const float* __restrict__ ow,
    unsigned short* __restrict__ wbf, unsigned short* __restrict__ owbf) {
  int idx = blockIdx.x * 256 + threadIdx.x;  // 65536 float4s total
  float4 f;
  unsigned short* dst;
  if (idx < 49152) {
    f = ((const float4*)ipw)[idx];
    dst = wbf + idx * 4;
  } else {
    int j = idx - 49152;
    f = ((const float4*)ow)[j];
    dst = owbf + j * 4;
  }
  ushort4 u;
  u.x = f2bf(f.x); u.y = f2bf(f.y); u.z = f2bf(f.z); u.w = f2bf(f.w);
  *(ushort4*)dst = u;
}

// ---------------- Prep 2: x (b,C,S) fp32 -> xbfT (b,S,C) bf16 ----------------
__global__ __launch_bounds__(256) void transpose_x_kernel(
    const float* __restrict__ x, unsigned short* __restrict__ xbfT) {
  __shared__ __align__(16) unsigned short T[64 * 72];  // [s][c]
  const int tid = threadIdx.x;
  const int s0 = blockIdx.x * 64, c0 = blockIdx.y * 64, b = blockIdx.z;
  const int c_l = tid >> 2, q4 = tid & 3;
  const float4* src = (const float4*)(x + (((size_t)(b * CDIM + c0 + c_l)) << 12) + s0);
#pragma unroll
  for (int i = 0; i < 4; ++i) {
    int chunk = i * 4 + q4;
    float4 f = src[chunk];
    T[(chunk * 4 + 0) * 72 + c_l] = f2bf(f.x);
    T[(chunk * 4 + 1) * 72 + c_l] = f2bf(f.y);
    T[(chunk * 4 + 2) * 72 + c_l] = f2bf(f.z);
    T[(chunk * 4 + 3) * 72 + c_l] = f2bf(f.w);
  }
  __syncthreads();
  const int s_l = tid >> 2;
  unsigned short* drow = xbfT + ((size_t)((b << 12) + s0 + s_l)) * CDIM + c0;
#pragma unroll
  for (int i = 0; i < 2; ++i) {
    int chunk = i * 4 + q4;
    uint4 u = *(const uint4*)&T[s_l * 72 + chunk * 8];
    *(uint4*)(drow + chunk * 8) = u;
  }
}

// ---------------- Kernel 1: QKV projection, bf16 MFMA GEMM (128x64 tiles) ----
// q prescale = (1/8)*log2(e) so attention scores are already log2-domain.
__global__ __launch_bounds__(256) void qkv_gemm_kernel(
    const unsigned short* __restrict__ xbfT, const unsigned short* __restrict__ wbf,
    const float* __restrict__ ipb, unsigned short* __restrict__ q16,
    unsigned short* __restrict__ k16, unsigned short* __restrict__ vt16) {
  __shared__ __align__(16) unsigned short As[128 * LDA];  // [tok_l][k_l]
  __shared__ __align__(16) unsigned short Bs[64 * LDA];   // [cout_l][k_l]
  const int tid = threadIdx.x;
  const int wave = tid >> 6, lane = tid & 63;
  const int quad = lane >> 4, l16 = lane & 15;
  const int n0 = blockIdx.x * 64;    // c_out base (0..704)
  const int tok0 = blockIdx.y * 128; // token base within batch
  const int b = blockIdx.z;

  const int r1 = tid >> 2, c1 = tid & 3;  // A: rows r1, r1+64; 16B chunk c1
  const unsigned short* gA = xbfT + ((size_t)(b * S_TOK + tok0 + r1)) * CDIM + c1 * 8;
  const unsigned short* gB = wbf + ((size_t)(n0 + r1)) * CDIM + c1 * 8;  // B: 64 rows
  unsigned short* wA = &As[r1 * LDA + c1 * 8];
  unsigned short* wB = &Bs[r1 * LDA + c1 * 8];

  floatx4 acc[2][4];
#pragma unroll
  for (int mt = 0; mt < 2; ++mt)
#pragma unroll
    for (int nt = 0; nt < 4; ++nt) acc[mt][nt] = (floatx4){0.f, 0.f, 0.f, 0.f};

  uint4 a0p = *(const uint4*)(gA);
  uint4 a1p = *(const uint4*)(gA + 64 * CDIM);
  uint4 b0p = *(const uint4*)(gB);

  for (int ks = 0; ks < 8; ++ks) {
    __syncthreads();
    *(uint4*)wA = a0p;
    *(uint4*)(wA + 64 * LDA) = a1p;
    *(uint4*)wB = b0p;
    __syncthreads();
    if (ks < 7) {
      int off = (ks + 1) * 32;
      a0p = *(const uint4*)(gA + off);
      a1p = *(const uint4*)(gA + 64 * CDIM + off);
      b0p = *(const uint4*)(gB + off);
    }
    short8 af[2], bf[4];
#pragma unroll
    for (int mt = 0; mt < 2; ++mt)
      af[mt] = *(const short8*)&As[(wave * 32 + mt * 16 + l16) * LDA + quad * 8];
#pragma unroll
    for (int nt = 0; nt < 4; ++nt)
      bf[nt] = *(const short8*)&Bs[(nt * 16 + l16) * LDA + quad * 8];
#pragma unroll
    for (int mt = 0; mt < 2; ++mt)
#pragma unroll
      for (int nt = 0; nt < 4; ++nt)
        acc[mt][nt] = __builtin_amdgcn_mfma_f32_16x16x32_bf16(af[mt], bf[nt], acc[mt][nt], 0, 0, 0);
  }

  const int slab = n0 >> 8;  // 0=q, 1=k, 2=v
  int cb[4];
  float bias4[4];
#pragma unroll
  for (int nt = 0; nt < 4; ++nt) {
    cb[nt] = n0 + nt * 16 + l16;
    bias4[nt] = ipb[cb[nt]];
  }
  if (slab == 2) {  // v -> vt16[bh][dh][tok]
#pragma unroll
    for (int mt = 0; mt < 2; ++mt) {
      int tok = tok0 + wave * 32 + mt * 16 + quad * 4;
#pragma unroll
      for (int nt = 0; nt < 4; ++nt) {
        int dh = cb[nt] & 63, h = (cb[nt] >> 6) & 3;
        ushort4 u;
        u.x = f2bf(acc[mt][nt][0] + bias4[nt]);
        u.y = f2bf(acc[mt][nt][1] + bias4[nt]);
        u.z = f2bf(acc[mt][nt][2] + bias4[nt]);
        u.w = f2bf(acc[mt][nt][3] + bias4[nt]);
        *(ushort4*)&vt16[((size_t)((b * NHEADS + h) * HDIM + dh)) * S_TOK + tok] = u;
      }
    }
  } else {
    unsigned short* dst = slab ? k16 : q16;
    const float sc = slab ? 1.0f : 0.125f * LOG2E;
#pragma unroll
    for (int mt = 0; mt < 2; ++mt)
#pragma unroll
      for (int nt = 0; nt < 4; ++nt) {
        int dh = cb[nt] & 63, h = (cb[nt] >> 6) & 3;
        size_t base = ((size_t)(b * NHEADS + h) * S_TOK);
#pragma unroll
        for (int r = 0; r < 4; ++r) {
          int tok = tok0 + wave * 32 + mt * 16 + quad * 4 + r;
          dst[(base + tok) * HDIM + dh] = f2bf((acc[mt][nt][r] + bias4[nt]) * sc);
        }
      }
  }
}

// ---------------- Kernel 2: flash attention, fixed-max softmax, 4-way split --
// Grid (32 q-tiles, 8 bh, 4 splits). Block: 4 waves x 32 q-rows, 16 key-tiles.
// K/V B-fragments reused across 2 m-tiles per wave -> 20 b128 reads per
// 32q x 64k unit (vs 36 at 16 rows/wave). Writes unnormalized partials.
__global__ __launch_bounds__(256) void attn_kernel(
    const unsigned short* __restrict__ q16,
    const unsigned short* __restrict__ k16,
    const unsigned short* __restrict__ vt16,
    unsigned short* __restrict__ op, float* __restrict__ lp) {
  __shared__ __align__(16) unsigned short Ks[64 * LSK];      // [key][dd]
  __shared__ __align__(16) unsigned short Vt[64 * LSK];      // [d][key]
  __shared__ __align__(16) unsigned short Ps[4 * 32 * LSK];  // per-wave [qrow][key]

  const int tid = threadIdx.x;
  const int wave = tid >> 6;
  const int lane = tid & 63;
  const int quad = lane >> 4;
  const int l16 = lane & 15;
  const int bh = blockIdx.y;
  const int q0 = blockIdx.x * 128;
  const int split = blockIdx.z;
  const int kt0 = split * 16;

  // Q A-fragments for 2 m-tiles (loop-invariant)
  short8 qf[2][2];
#pragma unroll
  for (int mt = 0; mt < 2; ++mt) {
    const unsigned short* qg =
        q16 + ((size_t)bh * S_TOK + q0 + wave * 32 + mt * 16 + l16) * HDIM + quad * 8;
    qf[mt][0] = *(const short8*)(qg);
    qf[mt][1] = *(const short8*)(qg + 32);
  }

  const int sr = tid >> 3, scc = tid & 7;
  const unsigned short* kg = k16 + ((size_t)bh * S_TOK + sr) * HDIM + scc * 8;
  const unsigned short* vg = vt16 + ((size_t)bh * HDIM + sr) * S_TOK + scc * 8;
  unsigned short* ksw = &Ks[sr * LSK + scc * 8];
  unsigned short* vtw = &Vt[sr * LSK + scc * 8];

  floatx4 O[2][4];
  float lsum[2][4];
#pragma unroll
  for (int mt = 0; mt < 2; ++mt)
#pragma unroll
    for (int nt = 0; nt < 4; ++nt) O[mt][nt] = (floatx4){0.f, 0.f, 0.f, 0.f};
#pragma unroll
  for (int mt = 0; mt < 2; ++mt)
#pragma unroll
    for (int r = 0; r < 4; ++r) lsum[mt][r] = 0.f;

  uint4 k0r = *(const uint4*)(kg + (size_t)kt0 * 64 * HDIM);
  uint4 k1r = *(const uint4*)(kg + (size_t)kt0 * 64 * HDIM + 32 * HDIM);
  uint4 v0r = *(const uint4*)(vg + kt0 * 64);
  uint4 v1r = *(const uint4*)(vg + kt0 * 64 + (size_t)32 * S_TOK);

  for (int t = 0; t < 16; ++t) {
    __syncthreads();
    *(uint4*)ksw = k0r;
    *(uint4*)(ksw + 32 * LSK) = k1r;
    *(uint4*)vtw = v0r;
    *(uint4*)(vtw + 32 * LSK) = v1r;
    __syncthreads();
    if (t < 15) {
      const unsigned short* kgn = kg + (size_t)(kt0 + t + 1) * 64 * HDIM;
      const unsigned short* vgn = vg + (kt0 + t + 1) * 64;
      k0r = *(const uint4*)(kgn);
      k1r = *(const uint4*)(kgn + 32 * HDIM);
      v0r = *(const uint4*)(vgn);
      v1r = *(const uint4*)(vgn + (size_t)32 * S_TOK);
    }

    // ---- S_log2 = Q K^T; K-frags shared across both m-tiles
    floatx4 sc[2][4];
#pragma unroll
    for (int nt = 0; nt < 4; ++nt) {
      short8 kf0 = *(const short8*)(&Ks[(nt * 16 + l16) * LSK + quad * 8]);
      short8 kf1 = *(const short8*)(&Ks[(nt * 16 + l16) * LSK + 32 + quad * 8]);
#pragma unroll
      for (int mt = 0; mt < 2; ++mt) {
        floatx4 c = (floatx4){0.f, 0.f, 0.f, 0.f};
        c = __builtin_amdgcn_mfma_f32_16x16x32_bf16(qf[mt][0], kf0, c, 0, 0, 0);
        c = __builtin_amdgcn_mfma_f32_16x16x32_bf16(qf[mt][1], kf1, c, 0, 0, 0);
        sc[mt][nt] = c;
      }
    }

    // ---- fixed-max softmax: p = 2^score, no in-loop reductions
    unsigned short* pw = &Ps[(wave * 32) * LSK];
#pragma unroll
    for (int mt = 0; mt < 2; ++mt)
#pragma unroll
      for (int nt = 0; nt < 4; ++nt)
#pragma unroll
        for (int r = 0; r < 4; ++r) {
          float p = __builtin_amdgcn_exp2f(sc[mt][nt][r]);
          lsum[mt][r] += p;
          pw[(mt * 16 + quad * 4 + r) * LSK + nt * 16 + l16] = f2bf(p);
        }

    // ---- O += P V; V-frags shared across both m-tiles
    short8 pf[2][2];
#pragma unroll
    for (int mt = 0; mt < 2; ++mt) {
      pf[mt][0] = *(const short8*)(&pw[(mt * 16 + l16) * LSK + quad * 8]);
      pf[mt][1] = *(const short8*)(&pw[(mt * 16 + l16) * LSK + 32 + quad * 8]);
    }
#pragma unroll
    for (int nt = 0; nt < 4; ++nt) {
      short8 vf0 = *(const short8*)(&Vt[(nt * 16 + l16) * LSK + quad * 8]);
      short8 vf1 = *(const short8*)(&Vt[(nt * 16 + l16) * LSK + 32 + quad * 8]);
#pragma unroll
      for (int mt = 0; mt < 2; ++mt) {
        O[mt][nt] = __builtin_amdgcn_mfma_f32_16x16x32_bf16(pf[mt][0], vf0, O[mt][nt], 0, 0, 0);
        O[mt][nt] = __builtin_amdgcn_mfma_f32_16x16x32_bf16(pf[mt][1], vf1, O[mt][nt], 0, 0, 0);
      }
    }
  }

  // epilogue: l-reduction once; write bf16 O-partials + fp32 l-partials
  unsigned short* op_s = op + (size_t)split * 2097152;
  float* lp_s = lp + (size_t)split * 32768;
#pragma unroll
  for (int mt = 0; mt < 2; ++mt)
#pragma unroll
    for (int r = 0; r < 4; ++r) {
      float ls = lsum[mt][r];
      ls += __shfl_xor(ls, 1);
      ls += __shfl_xor(ls, 2);
      ls += __shfl_xor(ls, 4);
      ls += __shfl_xor(ls, 8);
      int row = q0 + wave * 32 + mt * 16 + quad * 4 + r;
#pragma unroll
      for (int nt = 0; nt < 4; ++nt)
        op_s[((size_t)bh * S_TOK + row) * HDIM + nt * 16 + l16] = f2bf(O[mt][nt][r]);
      if (l16 == 0) lp_s[bh * S_TOK + row] = ls;
    }
}

// ---------------- Kernel 2b: merge 4 key-split partials -> ab16 (b,S,C) ------
__global__ __launch_bounds__(256) void merge_kernel(
    const unsigned short* __restrict__ op, const float* __restrict__ lp,
    unsigned short* __restrict__ ab16) {
  int idx = blockIdx.x * 256 + threadIdx.x;  // 262144 threads
  int row = idx >> 3;                        // bh*4096+tok
  int ch = idx & 7;                          // dh octet
  float rinv = 1.0f / (lp[row] + lp[32768 + row] + lp[65536 + row] + lp[98304 + row]);
  float s[8];
#pragma unroll
  for (int i = 0; i < 8; ++i) s[i] = 0.f;
#pragma unroll
  for (int sp = 0; sp < 4; ++sp) {
    uint4 a = *(const uint4*)(op + (size_t)sp * 2097152 + (size_t)row * HDIM + ch * 8);
    const unsigned* au = (const unsigned*)&a;
#pragma unroll
    for (int i = 0; i < 4; ++i) {
      s[i * 2] += bf2f((unsigned short)(au[i] & 0xffff));
      s[i * 2 + 1] += bf2f((unsigned short)(au[i] >> 16));
    }
  }
  ushort4 o[2];
#pragma unroll
  for (int i = 0; i < 8; ++i) ((unsigned short*)o)[i] = f2bf(s[i] * rinv);
  int bh = row >> 12, tok = row & 4095;
  int b = bh >> 2, h = bh & 3;
  unsigned short* dst = ab16 + ((size_t)(b * S_TOK + tok)) * CDIM + h * HDIM + ch * 8;
  *(ushort4*)dst = o[0];
  *(ushort4*)(dst + 4) = o[1];
}

// ---------------- Kernel 3: out projection (MFMA) + LayerNorm + transpose ----
__global__ __launch_bounds__(256) void out_ln_gemm_kernel(
    const unsigned short* __restrict__ ab16, const unsigned short* __restrict__ owbf,
    const float* __restrict__ obias, const float* __restrict__ lng,
    const float* __restrict__ lnb, float* __restrict__ out) {
  __shared__ __align__(16) unsigned short As[16 * LDA];
  __shared__ __align__(16) unsigned short Bs[256 * LDA];
  __shared__ __align__(16) float ys[16 * LDY];
  const int tid = threadIdx.x;
  const int wave = tid >> 6, lane = tid & 63;
  const int quad = lane >> 4, l16 = lane & 15;
  const int tok0 = blockIdx.x * 16;  // global token (b folded)

  const int ar = tid >> 4, ac = tid & 15;
  const unsigned short* gA = ab16 + ((size_t)(tok0 + ar)) * CDIM + ac * 2;
  unsigned short* wAp = &As[ar * LDA + ac * 2];
  const int br = tid >> 2, bc = tid & 3;
  const unsigned short* gB = owbf + ((size_t)br) * CDIM + bc * 8;
  unsigned short* wBp = &Bs[br * LDA + bc * 8];

  floatx4 acc[4];
#pragma unroll
  for (int nt = 0; nt < 4; ++nt) acc[nt] = (floatx4){0.f, 0.f, 0.f, 0.f};

  unsigned ap = *(const unsigned*)(gA);
  uint4 bp[4];
#pragma unroll
  for (int i = 0; i < 4; ++i) bp[i] = *(const uint4*)(gB + (size_t)i * 64 * CDIM);

  for (int ks = 0; ks < 8; ++ks) {
    __syncthreads();
    *(unsigned*)wAp = ap;
#pragma unroll
    for (int i = 0; i < 4; ++i) *(uint4*)(wBp + i * 64 * LDA) = bp[i];
    __syncthreads();
    if (ks < 7) {
      int off = (ks + 1) * 32;
      ap = *(const unsigned*)(gA + off);
#pragma unroll
      for (int i = 0; i < 4; ++i)
        bp[i] = *(const uint4*)(gB + (size_t)i * 64 * CDIM + off);
    }
    short8 af = *(const short8*)&As[l16 * LDA + quad * 8];
    short8 bf[4];
#pragma unroll
    for (int nt = 0; nt < 4; ++nt)
      bf[nt] = *(const short8*)&Bs[(wave * 64 + nt * 16 + l16) * LDA + quad * 8];
#pragma unroll
    for (int nt = 0; nt < 4; ++nt)
      acc[nt] = __builtin_amdgcn_mfma_f32_16x16x32_bf16(af, bf[nt], acc[nt], 0, 0, 0);
  }

#pragma unroll
  for (int nt = 0; nt < 4; ++nt) {
    int c = wave * 64 + nt * 16 + l16;
    float bo = obias[c];
#pragma unroll
    for (int r = 0; r < 4; ++r)
      ys[(quad * 4 + r) * LDY + c] = acc[nt][r] + bo;
  }
  __syncthreads();

  const int gtok = tid >> 4, lx = tid & 15;
  float sum = 0.f, ssq = 0.f;
#pragma unroll
  for (int i = 0; i < 16; ++i) {
    float v = ys[gtok * LDY + i * 16 + lx];
    sum += v;
    ssq += v * v;
  }
  sum += __shfl_xor(sum, 1); ssq += __shfl_xor(ssq, 1);
  sum += __shfl_xor(sum, 2); ssq += __shfl_xor(ssq, 2);
  sum += __shfl_xor(sum, 4); ssq += __shfl_xor(ssq, 4);
  sum += __shfl_xor(sum, 8); ssq += __shfl_xor(ssq, 8);
  float mu = sum * (1.f / 256.f);
  float var = ssq * (1.f / 256.f) - mu * mu;
  float rstd = rsqrtf(var + 1e-5f);
  const int b2 = tok0 >> 12;
  const int sl = (tok0 & 4095) + gtok;
#pragma unroll
  for (int i = 0; i < 16; ++i) {
    int c = i * 16 + lx;
    float v = ys[gtok * LDY + c];
    out[(((size_t)(b2 * CDIM + c)) << 12) + sl] = (v - mu) * rstd * lng[c] + lnb[c];
  }
}

extern "C" void kernel_launch(void* const* d_in, const int* in_sizes, int n_in,
                              void* d_out, int out_size, void* d_ws, size_t ws_size,
                              hipStream_t stream) {
  const float* x = (const float*)d_in[0];
  const float* ipw = (const float*)d_in[1];
  const float* ipb = (const float*)d_in[2];
  const float* ow = (const float*)d_in[3];
  const float* ob = (const float*)d_in[4];
  const float* lng = (const float*)d_in[5];
  const float* lnb = (const float*)d_in[6];
  float* out = (float*)d_out;
  // workspace (ushort units), total ~37.3 MiB:
  unsigned short* wbf = (unsigned short*)d_ws;       // 196608
  unsigned short* owbf = wbf + 196608;               // 65536
  unsigned short* xbfT = owbf + 65536;               // 2097152
  unsigned short* q16 = xbfT + 2097152;              // 2097152
  unsigned short* k16 = q16 + 2097152;               // 2097152
  unsigned short* vt16 = k16 + 2097152;              // 2097152
  unsigned short* op = vt16 + 2097152;               // 4 x 2097152 (bf16 O-partials)
  unsigned short* ab16 = op + 8388608;               // 2097152
  float* lp = (float*)(ab16 + 2097152);              // 4 x 32768 fp32

  convert_w_kernel<<<256, 256, 0, stream>>>(ipw, ow, wbf, owbf);
  transpose_x_kernel<<<dim3(64, 4, 2), 256, 0, stream>>>(x, xbfT);
  qkv_gemm_kernel<<<dim3(12, 32, 2), 256, 0, stream>>>(xbfT, wbf, ipb, q16, k16, vt16);
  attn_kernel<<<dim3(32, 8, 4), 256, 0, stream>>>(q16, k16, vt16, op, lp);
  merge_kernel<<<1024, 256, 0, stream>>>(op, lp, ab16);
  out_ln_gemm_kernel<<<512, 256, 0, stream>>>(ab16, owbf, ob, lng, lnb, out);
}

// Round 7
// 167.558 us; speedup vs baseline: 4.9997x; 1.0352x over previous
//
#include <hip/hip_runtime.h>
#include <cstddef>

#define S_TOK 4096
#define CDIM 256
#define NHEADS 4
#define HDIM 64
#define LSK 72   // ushort stride for attention LDS rows
#define LDA 36   // ushort stride for GEMM LDS tiles (32 k + 4 pad)
#define LDY 264  // float stride for GEMM2 LN buffer
#define LOG2E 1.44269504f

typedef __attribute__((ext_vector_type(8))) short short8;
typedef __attribute__((ext_vector_type(4))) float floatx4;

__device__ inline unsigned short f2bf(float f) {
  union { float f; unsigned u; } v;
  v.f = f;
  unsigned r = v.u + 0x7fff + ((v.u >> 16) & 1);  // round-to-nearest-even
  return (unsigned short)(r >> 16);
}
__device__ inline float bf2f(unsigned short u) {
  union { unsigned u; float f; } v;
  v.u = ((unsigned)u) << 16;
  return v.f;
}

// ---------------- Prep: weights fp32->bf16 (blocks 0..255) + x transpose -----
// blocks 256..767: x (b,C,S) fp32 -> xbfT (b,S,C) bf16 via 64x64 LDS tiles.
__global__ __launch_bounds__(256) void prep_kernel(
    const float* __restrict__ x, const float* __restrict__ ipw,
    const float* __restrict__ ow, unsigned short* __restrict__ wbf,
    unsigned short* __restrict__ owbf, unsigned short* __restrict__ xbfT) {
  __shared__ __align__(16) unsigned short T[64 * 72];
  const int tid = threadIdx.x;
  if (blockIdx.x < 256) {  // weight conversion: 65536 float4s
    int idx = blockIdx.x * 256 + tid;
    float4 f;
    unsigned short* dst;
    if (idx < 49152) {
      f = ((const float4*)ipw)[idx];
      dst = wbf + idx * 4;
    } else {
      int j = idx - 49152;
      f = ((const float4*)ow)[j];
      dst = owbf + j * 4;
    }
    ushort4 u;
    u.x = f2bf(f.x); u.y = f2bf(f.y); u.z = f2bf(f.z); u.w = f2bf(f.w);
    *(ushort4*)dst = u;
    return;
  }
  const int bid = blockIdx.x - 256;
  const int s0 = (bid & 63) * 64, c0 = ((bid >> 6) & 3) * 64, b = bid >> 8;
  const int c_l = tid >> 2, q4 = tid & 3;
  const float4* src = (const float4*)(x + (((size_t)(b * CDIM + c0 + c_l)) << 12) + s0);
#pragma unroll
  for (int i = 0; i < 4; ++i) {
    int chunk = i * 4 + q4;
    float4 f = src[chunk];
    T[(chunk * 4 + 0) * 72 + c_l] = f2bf(f.x);
    T[(chunk * 4 + 1) * 72 + c_l] = f2bf(f.y);
    T[(chunk * 4 + 2) * 72 + c_l] = f2bf(f.z);
    T[(chunk * 4 + 3) * 72 + c_l] = f2bf(f.w);
  }
  __syncthreads();
  const int s_l = tid >> 2;
  unsigned short* drow = xbfT + ((size_t)((b << 12) + s0 + s_l)) * CDIM + c0;
#pragma unroll
  for (int i = 0; i < 2; ++i) {
    int chunk = i * 4 + q4;
    uint4 u = *(const uint4*)&T[s_l * 72 + chunk * 8];
    *(uint4*)(drow + chunk * 8) = u;
  }
}

// ---------------- Kernel 1: QKV projection, bf16 MFMA GEMM (128x64 tiles) ----
// q prescale = (1/8)*log2(e) so attention scores are already log2-domain.
__global__ __launch_bounds__(256) void qkv_gemm_kernel(
    const unsigned short* __restrict__ xbfT, const unsigned short* __restrict__ wbf,
    const float* __restrict__ ipb, unsigned short* __restrict__ q16,
    unsigned short* __restrict__ k16, unsigned short* __restrict__ vt16) {
  __shared__ __align__(16) unsigned short As[128 * LDA];  // [tok_l][k_l]
  __shared__ __align__(16) unsigned short Bs[64 * LDA];   // [cout_l][k_l]
  const int tid = threadIdx.x;
  const int wave = tid >> 6, lane = tid & 63;
  const int quad = lane >> 4, l16 = lane & 15;
  const int n0 = blockIdx.x * 64;    // c_out base (0..704)
  const int tok0 = blockIdx.y * 128; // token base within batch
  const int b = blockIdx.z;

  const int r1 = tid >> 2, c1 = tid & 3;  // A: rows r1, r1+64; 16B chunk c1
  const unsigned short* gA = xbfT + ((size_t)(b * S_TOK + tok0 + r1)) * CDIM + c1 * 8;
  const unsigned short* gB = wbf + ((size_t)(n0 + r1)) * CDIM + c1 * 8;  // B: 64 rows
  unsigned short* wA = &As[r1 * LDA + c1 * 8];
  unsigned short* wB = &Bs[r1 * LDA + c1 * 8];

  floatx4 acc[2][4];
#pragma unroll
  for (int mt = 0; mt < 2; ++mt)
#pragma unroll
    for (int nt = 0; nt < 4; ++nt) acc[mt][nt] = (floatx4){0.f, 0.f, 0.f, 0.f};

  uint4 a0p = *(const uint4*)(gA);
  uint4 a1p = *(const uint4*)(gA + 64 * CDIM);
  uint4 b0p = *(const uint4*)(gB);

  for (int ks = 0; ks < 8; ++ks) {
    __syncthreads();
    *(uint4*)wA = a0p;
    *(uint4*)(wA + 64 * LDA) = a1p;
    *(uint4*)wB = b0p;
    __syncthreads();
    if (ks < 7) {
      int off = (ks + 1) * 32;
      a0p = *(const uint4*)(gA + off);
      a1p = *(const uint4*)(gA + 64 * CDIM + off);
      b0p = *(const uint4*)(gB + off);
    }
    short8 af[2], bf[4];
#pragma unroll
    for (int mt = 0; mt < 2; ++mt)
      af[mt] = *(const short8*)&As[(wave * 32 + mt * 16 + l16) * LDA + quad * 8];
#pragma unroll
    for (int nt = 0; nt < 4; ++nt)
      bf[nt] = *(const short8*)&Bs[(nt * 16 + l16) * LDA + quad * 8];
#pragma unroll
    for (int mt = 0; mt < 2; ++mt)
#pragma unroll
      for (int nt = 0; nt < 4; ++nt)
        acc[mt][nt] = __builtin_amdgcn_mfma_f32_16x16x32_bf16(af[mt], bf[nt], acc[mt][nt], 0, 0, 0);
  }

  const int slab = n0 >> 8;  // 0=q, 1=k, 2=v
  int cb[4];
  float bias4[4];
#pragma unroll
  for (int nt = 0; nt < 4; ++nt) {
    cb[nt] = n0 + nt * 16 + l16;
    bias4[nt] = ipb[cb[nt]];
  }
  if (slab == 2) {  // v -> vt16[bh][dh][tok]
#pragma unroll
    for (int mt = 0; mt < 2; ++mt) {
      int tok = tok0 + wave * 32 + mt * 16 + quad * 4;
#pragma unroll
      for (int nt = 0; nt < 4; ++nt) {
        int dh = cb[nt] & 63, h = (cb[nt] >> 6) & 3;
        ushort4 u;
        u.x = f2bf(acc[mt][nt][0] + bias4[nt]);
        u.y = f2bf(acc[mt][nt][1] + bias4[nt]);
        u.z = f2bf(acc[mt][nt][2] + bias4[nt]);
        u.w = f2bf(acc[mt][nt][3] + bias4[nt]);
        *(ushort4*)&vt16[((size_t)((b * NHEADS + h) * HDIM + dh)) * S_TOK + tok] = u;
      }
    }
  } else {
    unsigned short* dst = slab ? k16 : q16;
    const float sc = slab ? 1.0f : 0.125f * LOG2E;
#pragma unroll
    for (int mt = 0; mt < 2; ++mt)
#pragma unroll
      for (int nt = 0; nt < 4; ++nt) {
        int dh = cb[nt] & 63, h = (cb[nt] >> 6) & 3;
        size_t base = ((size_t)(b * NHEADS + h) * S_TOK);
#pragma unroll
        for (int r = 0; r < 4; ++r) {
          int tok = tok0 + wave * 32 + mt * 16 + quad * 4 + r;
          dst[(base + tok) * HDIM + dh] = f2bf((acc[mt][nt][r] + bias4[nt]) * sc);
        }
      }
  }
}

// ---------------- Kernel 2: flash attention, S^T trick, 4-way key split ------
// S^T = mfma(kf, qf): C-layout row=key, col=qrow -> lane's 4 exp'd values are
// 4 consecutive keys of ONE q-row => one ds_write_b64 into Ps[qrow][key].
// lsum is one scalar per lane per mt (2 end-of-kernel shuffles).
// Partials written in ab-layout (b, tok, C); merge fused into out_ln.
__global__ __launch_bounds__(256) void attn_kernel(
    const unsigned short* __restrict__ q16,
    const unsigned short* __restrict__ k16,
    const unsigned short* __restrict__ vt16,
    unsigned short* __restrict__ op, float* __restrict__ lp) {
  __shared__ __align__(16) unsigned short Ks[64 * LSK];      // [key][dd]
  __shared__ __align__(16) unsigned short Vt[64 * LSK];      // [d][key]
  __shared__ __align__(16) unsigned short Ps[4 * 32 * LSK];  // per-wave [qrow][key]

  const int tid = threadIdx.x;
  const int wave = tid >> 6;
  const int lane = tid & 63;
  const int quad = lane >> 4;
  const int l16 = lane & 15;
  const int bh = blockIdx.y;
  const int q0 = blockIdx.x * 128;
  const int split = blockIdx.z;
  const int kt0 = split * 16;

  // Q fragments for 2 m-tiles (loop-invariant); same per-lane layout as A and B
  short8 qf[2][2];
#pragma unroll
  for (int mt = 0; mt < 2; ++mt) {
    const unsigned short* qg =
        q16 + ((size_t)bh * S_TOK + q0 + wave * 32 + mt * 16 + l16) * HDIM + quad * 8;
    qf[mt][0] = *(const short8*)(qg);
    qf[mt][1] = *(const short8*)(qg + 32);
  }

  const int sr = tid >> 3, scc = tid & 7;
  const unsigned short* kg = k16 + ((size_t)bh * S_TOK + sr) * HDIM + scc * 8;
  const unsigned short* vg = vt16 + ((size_t)bh * HDIM + sr) * S_TOK + scc * 8;
  unsigned short* ksw = &Ks[sr * LSK + scc * 8];
  unsigned short* vtw = &Vt[sr * LSK + scc * 8];

  floatx4 O[2][4];
  float lsum[2] = {0.f, 0.f};
#pragma unroll
  for (int mt = 0; mt < 2; ++mt)
#pragma unroll
    for (int nt = 0; nt < 4; ++nt) O[mt][nt] = (floatx4){0.f, 0.f, 0.f, 0.f};

  uint4 k0r = *(const uint4*)(kg + (size_t)kt0 * 64 * HDIM);
  uint4 k1r = *(const uint4*)(kg + (size_t)kt0 * 64 * HDIM + 32 * HDIM);
  uint4 v0r = *(const uint4*)(vg + kt0 * 64);
  uint4 v1r = *(const uint4*)(vg + kt0 * 64 + (size_t)32 * S_TOK);

  unsigned short* pw = &Ps[(wave * 32) * LSK];

  for (int t = 0; t < 16; ++t) {
    __syncthreads();
    *(uint4*)ksw = k0r;
    *(uint4*)(ksw + 32 * LSK) = k1r;
    *(uint4*)vtw = v0r;
    *(uint4*)(vtw + 32 * LSK) = v1r;
    __syncthreads();
    if (t < 15) {
      const unsigned short* kgn = kg + (size_t)(kt0 + t + 1) * 64 * HDIM;
      const unsigned short* vgn = vg + (kt0 + t + 1) * 64;
      k0r = *(const uint4*)(kgn);
      k1r = *(const uint4*)(kgn + 32 * HDIM);
      v0r = *(const uint4*)(vgn);
      v1r = *(const uint4*)(vgn + (size_t)32 * S_TOK);
    }

    // ---- S^T = K Q^T per (kt16, mt); exp2 + packed b64 store to Ps[qrow][key]
#pragma unroll
    for (int kt = 0; kt < 4; ++kt) {
      short8 kf0 = *(const short8*)(&Ks[(kt * 16 + l16) * LSK + quad * 8]);
      short8 kf1 = *(const short8*)(&Ks[(kt * 16 + l16) * LSK + 32 + quad * 8]);
#pragma unroll
      for (int mt = 0; mt < 2; ++mt) {
        floatx4 c = (floatx4){0.f, 0.f, 0.f, 0.f};
        c = __builtin_amdgcn_mfma_f32_16x16x32_bf16(kf0, qf[mt][0], c, 0, 0, 0);
        c = __builtin_amdgcn_mfma_f32_16x16x32_bf16(kf1, qf[mt][1], c, 0, 0, 0);
        float p0 = __builtin_amdgcn_exp2f(c[0]);
        float p1 = __builtin_amdgcn_exp2f(c[1]);
        float p2 = __builtin_amdgcn_exp2f(c[2]);
        float p3 = __builtin_amdgcn_exp2f(c[3]);
        lsum[mt] += (p0 + p1) + (p2 + p3);
        uint2 pk;
        pk.x = ((unsigned)f2bf(p1) << 16) | f2bf(p0);
        pk.y = ((unsigned)f2bf(p3) << 16) | f2bf(p2);
        *(uint2*)&pw[(mt * 16 + l16) * LSK + kt * 16 + quad * 4] = pk;
      }
    }

    // ---- O += P V ; V-frags shared across both m-tiles
    short8 pf[2][2];
#pragma unroll
    for (int mt = 0; mt < 2; ++mt) {
      pf[mt][0] = *(const short8*)(&pw[(mt * 16 + l16) * LSK + quad * 8]);
      pf[mt][1] = *(const short8*)(&pw[(mt * 16 + l16) * LSK + 32 + quad * 8]);
    }
#pragma unroll
    for (int nt = 0; nt < 4; ++nt) {
      short8 vf0 = *(const short8*)(&Vt[(nt * 16 + l16) * LSK + quad * 8]);
      short8 vf1 = *(const short8*)(&Vt[(nt * 16 + l16) * LSK + 32 + quad * 8]);
#pragma unroll
      for (int mt = 0; mt < 2; ++mt) {
        O[mt][nt] = __builtin_amdgcn_mfma_f32_16x16x32_bf16(pf[mt][0], vf0, O[mt][nt], 0, 0, 0);
        O[mt][nt] = __builtin_amdgcn_mfma_f32_16x16x32_bf16(pf[mt][1], vf1, O[mt][nt], 0, 0, 0);
      }
    }
  }

  // epilogue: partials in ab-layout; l-partials per (bh,row)
  const int b = bh >> 2, h = bh & 3;
  unsigned short* op_s = op + (size_t)split * 2097152;
  float* lp_s = lp + (size_t)split * 32768;
#pragma unroll
  for (int mt = 0; mt < 2; ++mt) {
    float ls = lsum[mt];
    ls += __shfl_xor(ls, 16);
    ls += __shfl_xor(ls, 32);
    if (quad == 0)
      lp_s[bh * S_TOK + q0 + wave * 32 + mt * 16 + l16] = ls;
#pragma unroll
    for (int r = 0; r < 4; ++r) {
      int row = q0 + wave * 32 + mt * 16 + quad * 4 + r;
#pragma unroll
      for (int nt = 0; nt < 4; ++nt)
        op_s[((size_t)(b * S_TOK + row)) * CDIM + h * HDIM + nt * 16 + l16] =
            f2bf(O[mt][nt][r]);
    }
  }
}

// merged A-element: sum 4 split partials, scale by 1/l, pack 2 bf16
__device__ inline unsigned merge2(const unsigned short* op, size_t off, float rinv) {
  float lo = 0.f, hi = 0.f;
#pragma unroll
  for (int sp = 0; sp < 4; ++sp) {
    unsigned u = *(const unsigned*)(op + (size_t)sp * 2097152 + off);
    lo += bf2f((unsigned short)(u & 0xffff));
    hi += bf2f((unsigned short)(u >> 16));
  }
  return ((unsigned)f2bf(hi * rinv) << 16) | f2bf(lo * rinv);
}

// ---------------- Kernel 3: merge + out projection (MFMA) + LayerNorm --------
__global__ __launch_bounds__(256) void out_ln_gemm_kernel(
    const unsigned short* __restrict__ op, const float* __restrict__ lp,
    const unsigned short* __restrict__ owbf, const float* __restrict__ obias,
    const float* __restrict__ lng, const float* __restrict__ lnb,
    float* __restrict__ out) {
  __shared__ __align__(16) unsigned short As[16 * LDA];
  __shared__ __align__(16) unsigned short Bs[256 * LDA];
  __shared__ __align__(16) float ys[16 * LDY];
  __shared__ float rsum[64];  // [tok_l][h]
  const int tid = threadIdx.x;
  const int wave = tid >> 6, lane = tid & 63;
  const int quad = lane >> 4, l16 = lane & 15;
  const int tok0 = blockIdx.x * 16;  // global token (b folded)

  if (tid < 64) {
    int t = tid >> 2, h = tid & 3;
    int bb = tok0 >> 12;
    int idx = (bb * 4 + h) * 4096 + (tok0 & 4095) + t;
    rsum[t * 4 + h] =
        1.0f / (lp[idx] + lp[32768 + idx] + lp[65536 + idx] + lp[98304 + idx]);
  }
  __syncthreads();

  const int ar = tid >> 4, ac = tid & 15;
  const size_t abase = (size_t)(tok0 + ar) * CDIM + ac * 2;
  unsigned short* wAp = &As[ar * LDA + ac * 2];
  const int br = tid >> 2, bc = tid & 3;
  const unsigned short* gB = owbf + ((size_t)br) * CDIM + bc * 8;
  unsigned short* wBp = &Bs[br * LDA + bc * 8];

  floatx4 acc[4];
#pragma unroll
  for (int nt = 0; nt < 4; ++nt) acc[nt] = (floatx4){0.f, 0.f, 0.f, 0.f};

  unsigned ap = merge2(op, abase, rsum[ar * 4]);
  uint4 bp[4];
#pragma unroll
  for (int i = 0; i < 4; ++i) bp[i] = *(const uint4*)(gB + (size_t)i * 64 * CDIM);

  for (int ks = 0; ks < 8; ++ks) {
    __syncthreads();
    *(unsigned*)wAp = ap;
#pragma unroll
    for (int i = 0; i < 4; ++i) *(uint4*)(wBp + i * 64 * LDA) = bp[i];
    __syncthreads();
    if (ks < 7) {
      int off = (ks + 1) * 32;
      ap = merge2(op, abase + off, rsum[ar * 4 + ((ks + 1) >> 1)]);
#pragma unroll
      for (int i = 0; i < 4; ++i)
        bp[i] = *(const uint4*)(gB + (size_t)i * 64 * CDIM + off);
    }
    short8 af = *(const short8*)&As[l16 * LDA + quad * 8];
    short8 bf[4];
#pragma unroll
    for (int nt = 0; nt < 4; ++nt)
      bf[nt] = *(const short8*)&Bs[(wave * 64 + nt * 16 + l16) * LDA + quad * 8];
#pragma unroll
    for (int nt = 0; nt < 4; ++nt)
      acc[nt] = __builtin_amdgcn_mfma_f32_16x16x32_bf16(af, bf[nt], acc[nt], 0, 0, 0);
  }

#pragma unroll
  for (int nt = 0; nt < 4; ++nt) {
    int c = wave * 64 + nt * 16 + l16;
    float bo = obias[c];
#pragma unroll
    for (int r = 0; r < 4; ++r)
      ys[(quad * 4 + r) * LDY + c] = acc[nt][r] + bo;
  }
  __syncthreads();

  const int gtok = tid >> 4, lx = tid & 15;
  float sum = 0.f, ssq = 0.f;
#pragma unroll
  for (int i = 0; i < 16; ++i) {
    float v = ys[gtok * LDY + i * 16 + lx];
    sum += v;
    ssq += v * v;
  }
  sum += __shfl_xor(sum, 1); ssq += __shfl_xor(ssq, 1);
  sum += __shfl_xor(sum, 2); ssq += __shfl_xor(ssq, 2);
  sum += __shfl_xor(sum, 4); ssq += __shfl_xor(ssq, 4);
  sum += __shfl_xor(sum, 8); ssq += __shfl_xor(ssq, 8);
  float mu = sum * (1.f / 256.f);
  float var = ssq * (1.f / 256.f) - mu * mu;
  float rstd = rsqrtf(var + 1e-5f);
  const int b2 = tok0 >> 12;
  const int sl = (tok0 & 4095) + gtok;
#pragma unroll
  for (int i = 0; i < 16; ++i) {
    int c = i * 16 + lx;
    float v = ys[gtok * LDY + c];
    out[(((size_t)(b2 * CDIM + c)) << 12) + sl] = (v - mu) * rstd * lng[c] + lnb[c];
  }
}

extern "C" void kernel_launch(void* const* d_in, const int* in_sizes, int n_in,
                              void* d_out, int out_size, void* d_ws, size_t ws_size,
                              hipStream_t stream) {
  const float* x = (const float*)d_in[0];
  const float* ipw = (const float*)d_in[1];
  const float* ipb = (const float*)d_in[2];
  const float* ow = (const float*)d_in[3];
  const float* ob = (const float*)d_in[4];
  const float* lng = (const float*)d_in[5];
  const float* lnb = (const float*)d_in[6];
  float* out = (float*)d_out;
  // workspace (ushort units), total ~34.6 MiB:
  unsigned short* wbf = (unsigned short*)d_ws;       // 196608
  unsigned short* owbf = wbf + 196608;               // 65536
  unsigned short* xbfT = owbf + 65536;               // 2097152
  unsigned short* q16 = xbfT + 2097152;              // 2097152
  unsigned short* k16 = q16 + 2097152;               // 2097152
  unsigned short* vt16 = k16 + 2097152;              // 2097152
  unsigned short* op = vt16 + 2097152;               // 4 x 2097152 (ab-layout partials)
  float* lp = (float*)(op + 8388608);                // 4 x 32768 fp32

  prep_kernel<<<768, 256, 0, stream>>>(x, ipw, ow, wbf, owbf, xbfT);
  qkv_gemm_kernel<<<dim3(12, 32, 2), 256, 0, stream>>>(xbfT, wbf, ipb, q16, k16, vt16);
  attn_kernel<<<dim3(32, 8, 4), 256, 0, stream>>>(q16, k16, vt16, op, lp);
  out_ln_gemm_kernel<<<512, 256, 0, stream>>>(op, lp, owbf, ob, lng, lnb, out);
}